// Round 17
// baseline (269.523 us; speedup 1.0000x reference)
//
#include <hip/hip_runtime.h>
#include <hip/hip_bf16.h>

#define EMB 64
#define XCOLS 20
#define NSYMP 15
#define BSH 7
#define BSZ 128          // nodes per bucket (1<<BSH)
#define MAXNB 1024       // supports N <= 131072
#define PCHUNK 4096
#define TROWS 51         // 4 birth + 2 gender + 45 symp rows

typedef float sf16 __attribute__((ext_vector_type(16)));

// ---------------- bincount + fused table transform ----------------
// Blocks 0..50 additionally compute tL/tR rows (transform); all blocks do the
// bucket histogram. Saves one launch (R16 had transform separate).
__global__ void bincount_kernel(const int* __restrict__ ei, int* __restrict__ bcount,
                                int* __restrict__ offs, int E, int NB, int N,
                                const float* __restrict__ bt,
                                const float* __restrict__ gt,
                                const float* __restrict__ st,
                                const float* __restrict__ Wl,
                                const float* __restrict__ Wr,
                                float* __restrict__ tL, float* __restrict__ tR) {
    __shared__ int lh[MAXNB];
    __shared__ float row[EMB];
    for (int j = threadIdx.x; j < NB; j += 256) lh[j] = 0;
    int r = blockIdx.x;
    if (r < TROWS && threadIdx.x < EMB) {
        const float* src = (r < 4) ? (bt + r * EMB)
                         : (r < 6) ? (gt + (r - 4) * EMB)
                                   : (st + (r - 6) * EMB);
        row[threadIdx.x] = src[threadIdx.x];
    }
    __syncthreads();
    if (r < TROWS && threadIdx.x < EMB) {
        int d = threadIdx.x;
        float aL = 0.f, aR = 0.f;
#pragma unroll
        for (int k = 0; k < EMB; ++k) {
            float h = row[k];
            aL = fmaf(h, Wl[k * EMB + d], aL);
            aR = fmaf(h, Wr[k * EMB + d], aR);
        }
        tL[r * EMB + d] = aL;
        tR[r * EMB + d] = aR;
    }
    for (int i = blockIdx.x * 256 + threadIdx.x; i < E; i += gridDim.x * 256)
        atomicAdd(&lh[ei[E + i] >> BSH], 1);
    __syncthreads();
    for (int j = threadIdx.x; j < NB; j += 256)
        if (lh[j]) atomicAdd(&bcount[j], lh[j]);
    if (blockIdx.x == 0 && threadIdx.x == 0) offs[N] = E + N;   // slots incl. selfs
}

// ---------------- fused embed+GEMM1 via transformed tables ----------------
__global__ void embedgemm_kernel(const int* __restrict__ x,
                                 const float* __restrict__ tL,
                                 const float* __restrict__ tR,
                                 const float* __restrict__ bl,
                                 const float* __restrict__ br,
                                 float* __restrict__ outL, float* __restrict__ outR,
                                 int N) {
    __shared__ int xs[4 * XCOLS];
    int node = blockIdx.x * 4 + (threadIdx.x >> 6);
    int d = threadIdx.x & 63;
    if (threadIdx.x < 4 * XCOLS) {
        int n2 = blockIdx.x * 4 + threadIdx.x / XCOLS;
        int c = threadIdx.x % XCOLS;
        xs[threadIdx.x] = (n2 < N) ? x[n2 * XCOLS + c] : 0;
    }
    __syncthreads();
    if (node >= N) return;
    const int* xr = &xs[(threadIdx.x >> 6) * XCOLS];
    int rbi = xr[1] + 2 * xr[2] + 3 * xr[3];   // birth row 0..3
    int rg = 4 + xr[4];                        // gender row 4..5
    float fL = 0.f, fR = 0.f;
#pragma unroll
    for (int j = 0; j < NSYMP; ++j) {
        int row = 6 + j * 3 + xr[5 + j];
        fL += tL[row * EMB + d];
        fR += tR[row * EMB + d];
    }
    float aL = (tL[rbi * EMB + d] + tL[rg * EMB + d] + fL * (1.f / 15.f)) * (1.f / 3.f) + bl[d];
    float aR = (tR[rbi * EMB + d] + tR[rg * EMB + d] + fR * (1.f / 15.f)) * (1.f / 3.f) + br[d];
    outL[node * EMB + d] = aL;
    outR[node * EMB + d] = aR;
}

// ---------------- dual GEMM v8: scalar-cache h broadcast + register weights --
__global__ __launch_bounds__(256, 3)
void gemm_dual_kernel(const float* __restrict__ h,
                      const float* __restrict__ Wl, const float* __restrict__ bl,
                      const float* __restrict__ Wr, const float* __restrict__ br,
                      float* __restrict__ outL, float* __restrict__ outR, int N) {
    int lane = threadIdx.x & 63;
    int wv = threadIdx.x >> 6;
    float wl[EMB], wr[EMB];
#pragma unroll
    for (int k = 0; k < EMB; ++k) {
        wl[k] = Wl[k * EMB + lane];
        wr[k] = Wr[k * EMB + lane];
    }
    float blv = bl[lane], brv = br[lane];
    int stride = gridDim.x * 4;
    for (int node = blockIdx.x * 4 + wv; node < N; node += stride) {
        int un = __builtin_amdgcn_readfirstlane(node);
        const float* hrow = h + (size_t)un * EMB;
        sf16 va, vb, vc, vd;
        asm volatile("s_load_dwordx16 %0, %1, 0x0"  : "=s"(va) : "s"(hrow));
        asm volatile("s_load_dwordx16 %0, %1, 0x40" : "=s"(vb) : "s"(hrow));
        asm volatile("s_load_dwordx16 %0, %1, 0x80" : "=s"(vc) : "s"(hrow));
        asm volatile("s_load_dwordx16 %0, %1, 0xc0" : "=s"(vd) : "s"(hrow));
        asm volatile("s_waitcnt lgkmcnt(0)" ::: "memory");
        __builtin_amdgcn_sched_barrier(0);
        float l0 = blv, l1 = 0.f, r0 = brv, r1 = 0.f;
#pragma unroll
        for (int k = 0; k < 16; ++k) {
            l0 = fmaf(va[k], wl[k], l0);
            r0 = fmaf(va[k], wr[k], r0);
            l1 = fmaf(vb[k], wl[16 + k], l1);
            r1 = fmaf(vb[k], wr[16 + k], r1);
            l0 = fmaf(vc[k], wl[32 + k], l0);
            r0 = fmaf(vc[k], wr[32 + k], r0);
            l1 = fmaf(vd[k], wl[48 + k], l1);
            r1 = fmaf(vd[k], wr[48 + k], r1);
        }
        outL[(size_t)node * EMB + lane] = l0 + l1;
        outR[(size_t)node * EMB + lane] = r0 + r1;
    }
}

// ---------------- CSR build via 2-level radix partition ----------------
__global__ void bscan_kernel(const int* __restrict__ bcount, int* __restrict__ boffs,
                             int* __restrict__ bcursor, int NB) {
    __shared__ int s[1024];
    int t = threadIdx.x;
    int v0 = (t < NB) ? bcount[t] : 0;
    s[t] = v0;
    __syncthreads();
    for (int off = 1; off < 1024; off <<= 1) {
        int v = (t >= off) ? s[t - off] : 0;
        __syncthreads();
        s[t] += v;
        __syncthreads();
    }
    if (t < NB) {
        boffs[t + 1] = s[t];
        bcursor[t] = s[t] - v0;
    }
    if (t == 0) boffs[0] = 0;
}

__global__ void partition_kernel(const int* __restrict__ ei, int* __restrict__ bcursor,
                                 int* __restrict__ epart, int E, int NB) {
    __shared__ int lh[MAXNB];
    for (int j = threadIdx.x; j < NB; j += 256) lh[j] = 0;
    __syncthreads();
    int base = blockIdx.x * PCHUNK;
    int end = min(E, base + PCHUNK);
    for (int i = base + threadIdx.x; i < end; i += 256)
        atomicAdd(&lh[ei[E + i] >> BSH], 1);
    __syncthreads();
    for (int j = threadIdx.x; j < NB; j += 256) {
        int c = lh[j];
        lh[j] = c ? atomicAdd(&bcursor[j], c) : 0;
    }
    __syncthreads();
    for (int i = base + threadIdx.x; i < end; i += 256) {
        int dst = ei[E + i];
        int src = ei[i];
        int slot = atomicAdd(&lh[dst >> BSH], 1);
        epart[slot] = (src << BSH) | (dst & (BSZ - 1));
    }
}

// finalize: per-wave sub-histograms; node n gets deg+1 slots, slot 0 = self.
// Block 0 also zeroes the 128-int tail pad of ssrc so gat's unconditional
// prefetch over-reads always yield VALID row indices (lets gat drop its
// index-clamp cmp/cndmask chains entirely).
__global__ void finalize_kernel(const int* __restrict__ epart, const int* __restrict__ boffs,
                                int* __restrict__ offs, int* __restrict__ ssrc, int N,
                                int S /* = E + N, tail pad start */) {
    __shared__ int deg4[4][BSZ];
    __shared__ int pos[BSZ];
    __shared__ int cur4[4][BSZ];
    int b = blockIdx.x;
    int t = threadIdx.x;
    int w = t >> 6;
    int n0 = b << BSH;
    int r0 = boffs[b], r1 = boffs[b + 1];
    if (b == 0 && t < 128) ssrc[S + t] = 0;
    ((int*)deg4)[t] = 0;
    ((int*)deg4)[t + 256] = 0;
    __syncthreads();
    for (int e = r0 + t; e < r1; e += 256)
        atomicAdd(&deg4[w][epart[e] & (BSZ - 1)], 1);
    __syncthreads();
    int d0 = 0, d1 = 0, d2 = 0, sum = 0;
    if (t < BSZ) {
        d0 = deg4[0][t]; d1 = deg4[1][t]; d2 = deg4[2][t];
        sum = d0 + d1 + d2 + deg4[3][t];
        pos[t] = sum;
    }
    __syncthreads();
    for (int off = 1; off < BSZ; off <<= 1) {
        int v = (t < BSZ && t >= off) ? pos[t - off] : 0;
        __syncthreads();
        if (t < BSZ) pos[t] += v;
        __syncthreads();
    }
    if (t < BSZ) {
        int node = n0 + t;
        int base = r0 + n0 + (pos[t] - sum) + t;   // edges + self-slots before node
        if (node < N) {
            offs[node] = base;
            ssrc[base] = node;                     // self-loop at slot 0
        }
        cur4[0][t] = base + 1;
        cur4[1][t] = base + 1 + d0;
        cur4[2][t] = base + 1 + d0 + d1;
        cur4[3][t] = base + 1 + d0 + d1 + d2;
    }
    __syncthreads();
    for (int e = r0 + t; e < r1; e += 256) {
        int v = epart[e];
        int s = atomicAdd(&cur4[w][v & (BSZ - 1)], 1);
        ssrc[s] = v >> BSH;
    }
}

// ---------------- DPP cross-lane add (VALU pipe; compiler handles hazards) --
template <int CTRL>
__device__ __forceinline__ float dpp_add(float v) {
    union { float f; int i; } u, r;
    u.f = v;
    r.i = __builtin_amdgcn_update_dpp(0, u.i, CTRL, 0xF, 0xF, true);
    return v + r.f;
}

// ---------------- GATv2 layer: 8 edges per wave iteration, pipelined --------
// R16 lesson: 16-deep pipeline raised VGPR 28->40, occupancy 71->52%, net
// LOSS. Back to 8-deep. Index clamps removed (ssrc over-reads are always
// valid row indices: mid-stream reads hit the next node's edges, global tail
// is zeroed by finalize); only the p-masks remain, against hoisted e1g.
template <int L>
__global__ void gat_kernel(const float* __restrict__ xl, const float* __restrict__ xr,
                           const int* __restrict__ offs, const int* __restrict__ ssrc,
                           const float* __restrict__ att, const float* __restrict__ bias,
                           const float* __restrict__ linW, const float* __restrict__ linb,
                           float* __restrict__ out, int N) {
    int wid = blockIdx.x * 4 + (threadIdx.x >> 6);
    int lane = threadIdx.x & 63;
    if (wid >= N) return;
    int grp = lane >> 4;          // edge slot within the 4-wide half-batch
    int li = lane & 15;           // float4 channel slot
    unsigned cb = (unsigned)li << 2;

    const float LOG2E = 1.4426950408889634f;
    float4 att4 = *(const float4*)(att + cb);
    att4.x *= LOG2E; att4.y *= LOG2E; att4.z *= LOG2E; att4.w *= LOG2E;
    float4 bias4 = *(const float4*)(bias + cb);
    unsigned rb = (unsigned)wid << 6;
    float4 xr4 = *(const float4*)(xr + rb + cb);

    int e0 = offs[wid], e1 = offs[wid + 1];
    int e1a = e1 - grp;           // hoisted: t+grp < e1  <=>  t < e1a
    int e1b = e1 - 4 - grp;       // hoisted: t+4+grp < e1 <=> t < e1b

    float s = 0.f;
    float4 acc = {0.f, 0.f, 0.f, 0.f};

    // prologue: unconditional index loads (over-reads are valid, see above)
    unsigned sA = (unsigned)ssrc[e0 + grp];
    unsigned sB = (unsigned)ssrc[e0 + 4 + grp];

    for (int t = e0; t < e1; t += 8) {
        float4 a = *(const float4*)(xl + (sA << 6) + cb);
        float4 b = *(const float4*)(xl + (sB << 6) + cb);
        int tn = t + 8;
        unsigned nA = (unsigned)ssrc[tn + grp];
        unsigned nB = (unsigned)ssrc[tn + 4 + grp];
        bool vA = t < e1a;
        bool vB = t < e1b;

        float ux = a.x + xr4.x; ux = fmaxf(ux, 0.2f * ux);
        float uy = a.y + xr4.y; uy = fmaxf(uy, 0.2f * uy);
        float uz = a.z + xr4.z; uz = fmaxf(uz, 0.2f * uz);
        float uw = a.w + xr4.w; uw = fmaxf(uw, 0.2f * uw);
        float pa = att4.x * ux + att4.y * uy + att4.z * uz + att4.w * uw;
        pa = dpp_add<0xB1>(pa);
        pa = dpp_add<0x4E>(pa);
        if (L == 2) {
            pa = dpp_add<0x141>(pa);
            pa = dpp_add<0x140>(pa);
        }
        float pA = exp2f(pa);
        pA = vA ? pA : 0.f;
        s += pA;
        acc.x += pA * a.x; acc.y += pA * a.y; acc.z += pA * a.z; acc.w += pA * a.w;

        float vx = b.x + xr4.x; vx = fmaxf(vx, 0.2f * vx);
        float vy = b.y + xr4.y; vy = fmaxf(vy, 0.2f * vy);
        float vz = b.z + xr4.z; vz = fmaxf(vz, 0.2f * vz);
        float vw = b.w + xr4.w; vw = fmaxf(vw, 0.2f * vw);
        float pb = att4.x * vx + att4.y * vy + att4.z * vz + att4.w * vw;
        pb = dpp_add<0xB1>(pb);
        pb = dpp_add<0x4E>(pb);
        if (L == 2) {
            pb = dpp_add<0x141>(pb);
            pb = dpp_add<0x140>(pb);
        }
        float pB = exp2f(pb);
        pB = vB ? pB : 0.f;
        s += pB;
        acc.x += pB * b.x; acc.y += pB * b.y; acc.z += pB * b.z; acc.w += pB * b.w;

        sA = nA; sB = nB;
    }

    // combine the 4 edge groups (once per node)
    s += __shfl_xor(s, 16); s += __shfl_xor(s, 32);
    acc.x += __shfl_xor(acc.x, 16); acc.x += __shfl_xor(acc.x, 32);
    acc.y += __shfl_xor(acc.y, 16); acc.y += __shfl_xor(acc.y, 32);
    acc.z += __shfl_xor(acc.z, 16); acc.z += __shfl_xor(acc.z, 32);
    acc.w += __shfl_xor(acc.w, 16); acc.w += __shfl_xor(acc.w, 32);

    float inv = 1.f / (s + 1e-16f);
    if (L == 1) {
        float4 val;
        val.x = acc.x * inv + bias4.x;
        val.y = acc.y * inv + bias4.y;
        val.z = acc.z * inv + bias4.z;
        val.w = acc.w * inv + bias4.w;
        val.x = (val.x > 0.f) ? val.x : (__expf(val.x) - 1.f);
        val.y = (val.y > 0.f) ? val.y : (__expf(val.y) - 1.f);
        val.z = (val.z > 0.f) ? val.z : (__expf(val.z) - 1.f);
        val.w = (val.w > 0.f) ? val.w : (__expf(val.w) - 1.f);
        if (grp == 0) *(float4*)(out + rb + cb) = val;
    } else {
        float4 lw = *(const float4*)(linW + cb);
        float r = (acc.x * inv + bias4.x) * lw.x + (acc.y * inv + bias4.y) * lw.y +
                  (acc.z * inv + bias4.z) * lw.z + (acc.w * inv + bias4.w) * lw.w;
        r = dpp_add<0xB1>(r);
        r = dpp_add<0x4E>(r);
        r = dpp_add<0x141>(r);
        r = dpp_add<0x140>(r);
        if (lane == 0) out[wid] = r + linb[0];
    }
}

extern "C" void kernel_launch(void* const* d_in, const int* in_sizes, int n_in,
                              void* d_out, int out_size, void* d_ws, size_t ws_size,
                              hipStream_t stream) {
    const int* x = (const int*)d_in[0];
    const int* ei = (const int*)d_in[1];          // int32 marshalled
    const float* birth_tab = (const float*)d_in[2];
    const float* gender_tab = (const float*)d_in[3];
    const float* symp_tab = (const float*)d_in[4];
    const float* Wl1 = (const float*)d_in[5];
    const float* bl1 = (const float*)d_in[6];
    const float* Wr1 = (const float*)d_in[7];
    const float* br1 = (const float*)d_in[8];
    const float* att1 = (const float*)d_in[9];
    const float* bias1 = (const float*)d_in[10];
    const float* Wl2 = (const float*)d_in[11];
    const float* bl2 = (const float*)d_in[12];
    const float* Wr2 = (const float*)d_in[13];
    const float* br2 = (const float*)d_in[14];
    const float* att2 = (const float*)d_in[15];
    const float* bias2 = (const float*)d_in[16];
    const float* linW = (const float*)d_in[17];
    const float* linb = (const float*)d_in[18];
    float* outp = (float*)d_out;

    int N = in_sizes[0] / XCOLS;   // 100000
    int E = in_sizes[1] / 2;       // 1600000
    int NB = (N + BSZ - 1) >> BSH; // 782

    char* p = (char*)d_ws;
    auto alloc = [&](size_t bytes) {
        void* r = (void*)p;
        p += (bytes + 255) & ~(size_t)255;
        return r;
    };
    float* h0 = (float*)alloc((size_t)N * EMB * 4);
    float* bufA = (float*)alloc((size_t)N * EMB * 4);
    float* bufB = (float*)alloc((size_t)N * EMB * 4);
    int* bcount = (int*)alloc(MAXNB * 4);
    int* boffs = (int*)alloc((MAXNB + 1) * 4);
    int* bcursor = (int*)alloc(MAXNB * 4);
    int* offs = (int*)alloc((size_t)(N + 1) * 4);
    int* epart = (int*)alloc((size_t)E * 4);
    int* ssrc = (int*)alloc((size_t)(E + N + 128) * 4);  // edges + selfs + pad
    float* tL = (float*)alloc((size_t)TROWS * EMB * 4);
    float* tR = (float*)alloc((size_t)TROWS * EMB * 4);

    int ngrp = (N + 3) / 4;

    hipMemsetAsync(bcount, 0, MAXNB * 4, stream);
    // bincount (+ fused table transform)
    bincount_kernel<<<512, 256, 0, stream>>>(ei, bcount, offs, E, NB, N,
                                             birth_tab, gender_tab, symp_tab,
                                             Wl1, Wr1, tL, tR);
    bscan_kernel<<<1, 1024, 0, stream>>>(bcount, boffs, bcursor, NB);
    partition_kernel<<<(E + PCHUNK - 1) / PCHUNK, 256, 0, stream>>>(ei, bcursor, epart, E, NB);
    finalize_kernel<<<NB, 256, 0, stream>>>(epart, boffs, offs, ssrc, N, E + N);

    // node pipeline
    embedgemm_kernel<<<ngrp, 256, 0, stream>>>(x, tL, tR, bl1, br1, bufA, bufB, N);
    gat_kernel<1><<<ngrp, 256, 0, stream>>>(bufA, bufB, offs, ssrc, att1, bias1,
                                            nullptr, nullptr, h0, N);
    gemm_dual_kernel<<<768, 256, 0, stream>>>(h0, Wl2, bl2, Wr2, br2, bufA, bufB, N);
    gat_kernel<2><<<ngrp, 256, 0, stream>>>(bufA, bufB, offs, ssrc, att2, bias2,
                                            linW, linb, outp, N);
}

// Round 18
// 257.246 us; speedup vs baseline: 1.0477x; 1.0477x over previous
//
#include <hip/hip_runtime.h>
#include <hip/hip_bf16.h>

#define EMB 64
#define XCOLS 20
#define NSYMP 15
#define BSH 7
#define BSZ 128          // nodes per bucket (1<<BSH)
#define MAXNB 1024       // supports N <= 131072
#define PCHUNK 4096
#define TROWS 51         // 4 birth + 2 gender + 45 symp rows

typedef float sf16 __attribute__((ext_vector_type(16)));

// ---------------- bincount + fused table transform ----------------
__global__ void bincount_kernel(const int* __restrict__ ei, int* __restrict__ bcount,
                                int* __restrict__ offs, int E, int NB, int N,
                                const float* __restrict__ bt,
                                const float* __restrict__ gt,
                                const float* __restrict__ st,
                                const float* __restrict__ Wl,
                                const float* __restrict__ Wr,
                                float* __restrict__ tL, float* __restrict__ tR) {
    __shared__ int lh[MAXNB];
    __shared__ float row[EMB];
    for (int j = threadIdx.x; j < NB; j += 256) lh[j] = 0;
    int r = blockIdx.x;
    if (r < TROWS && threadIdx.x < EMB) {
        const float* src = (r < 4) ? (bt + r * EMB)
                         : (r < 6) ? (gt + (r - 4) * EMB)
                                   : (st + (r - 6) * EMB);
        row[threadIdx.x] = src[threadIdx.x];
    }
    __syncthreads();
    if (r < TROWS && threadIdx.x < EMB) {
        int d = threadIdx.x;
        float aL = 0.f, aR = 0.f;
#pragma unroll
        for (int k = 0; k < EMB; ++k) {
            float h = row[k];
            aL = fmaf(h, Wl[k * EMB + d], aL);
            aR = fmaf(h, Wr[k * EMB + d], aR);
        }
        tL[r * EMB + d] = aL;
        tR[r * EMB + d] = aR;
    }
    for (int i = blockIdx.x * 256 + threadIdx.x; i < E; i += gridDim.x * 256)
        atomicAdd(&lh[ei[E + i] >> BSH], 1);
    __syncthreads();
    for (int j = threadIdx.x; j < NB; j += 256)
        if (lh[j]) atomicAdd(&bcount[j], lh[j]);
    if (blockIdx.x == 0 && threadIdx.x == 0) offs[N] = E + N;   // slots incl. selfs
}

// ---------------- fused embed+GEMM1 via transformed tables ----------------
__global__ void embedgemm_kernel(const int* __restrict__ x,
                                 const float* __restrict__ tL,
                                 const float* __restrict__ tR,
                                 const float* __restrict__ bl,
                                 const float* __restrict__ br,
                                 float* __restrict__ outL, float* __restrict__ outR,
                                 int N) {
    __shared__ int xs[4 * XCOLS];
    int node = blockIdx.x * 4 + (threadIdx.x >> 6);
    int d = threadIdx.x & 63;
    if (threadIdx.x < 4 * XCOLS) {
        int n2 = blockIdx.x * 4 + threadIdx.x / XCOLS;
        int c = threadIdx.x % XCOLS;
        xs[threadIdx.x] = (n2 < N) ? x[n2 * XCOLS + c] : 0;
    }
    __syncthreads();
    if (node >= N) return;
    const int* xr = &xs[(threadIdx.x >> 6) * XCOLS];
    int rbi = xr[1] + 2 * xr[2] + 3 * xr[3];   // birth row 0..3
    int rg = 4 + xr[4];                        // gender row 4..5
    float fL = 0.f, fR = 0.f;
#pragma unroll
    for (int j = 0; j < NSYMP; ++j) {
        int row = 6 + j * 3 + xr[5 + j];
        fL += tL[row * EMB + d];
        fR += tR[row * EMB + d];
    }
    float aL = (tL[rbi * EMB + d] + tL[rg * EMB + d] + fL * (1.f / 15.f)) * (1.f / 3.f) + bl[d];
    float aR = (tR[rbi * EMB + d] + tR[rg * EMB + d] + fR * (1.f / 15.f)) * (1.f / 3.f) + br[d];
    outL[node * EMB + d] = aL;
    outR[node * EMB + d] = aR;
}

// ---------------- dual GEMM v8: scalar-cache h broadcast + register weights --
__global__ __launch_bounds__(256, 3)
void gemm_dual_kernel(const float* __restrict__ h,
                      const float* __restrict__ Wl, const float* __restrict__ bl,
                      const float* __restrict__ Wr, const float* __restrict__ br,
                      float* __restrict__ outL, float* __restrict__ outR, int N) {
    int lane = threadIdx.x & 63;
    int wv = threadIdx.x >> 6;
    float wl[EMB], wr[EMB];
#pragma unroll
    for (int k = 0; k < EMB; ++k) {
        wl[k] = Wl[k * EMB + lane];
        wr[k] = Wr[k * EMB + lane];
    }
    float blv = bl[lane], brv = br[lane];
    int stride = gridDim.x * 4;
    for (int node = blockIdx.x * 4 + wv; node < N; node += stride) {
        int un = __builtin_amdgcn_readfirstlane(node);
        const float* hrow = h + (size_t)un * EMB;
        sf16 va, vb, vc, vd;
        asm volatile("s_load_dwordx16 %0, %1, 0x0"  : "=s"(va) : "s"(hrow));
        asm volatile("s_load_dwordx16 %0, %1, 0x40" : "=s"(vb) : "s"(hrow));
        asm volatile("s_load_dwordx16 %0, %1, 0x80" : "=s"(vc) : "s"(hrow));
        asm volatile("s_load_dwordx16 %0, %1, 0xc0" : "=s"(vd) : "s"(hrow));
        asm volatile("s_waitcnt lgkmcnt(0)" ::: "memory");
        __builtin_amdgcn_sched_barrier(0);
        float l0 = blv, l1 = 0.f, r0 = brv, r1 = 0.f;
#pragma unroll
        for (int k = 0; k < 16; ++k) {
            l0 = fmaf(va[k], wl[k], l0);
            r0 = fmaf(va[k], wr[k], r0);
            l1 = fmaf(vb[k], wl[16 + k], l1);
            r1 = fmaf(vb[k], wr[16 + k], r1);
            l0 = fmaf(vc[k], wl[32 + k], l0);
            r0 = fmaf(vc[k], wr[32 + k], r0);
            l1 = fmaf(vd[k], wl[48 + k], l1);
            r1 = fmaf(vd[k], wr[48 + k], r1);
        }
        outL[(size_t)node * EMB + lane] = l0 + l1;
        outR[(size_t)node * EMB + lane] = r0 + r1;
    }
}

// ---------------- CSR build via 2-level radix partition ----------------
__global__ void bscan_kernel(const int* __restrict__ bcount, int* __restrict__ boffs,
                             int* __restrict__ bcursor, int NB) {
    __shared__ int s[1024];
    int t = threadIdx.x;
    int v0 = (t < NB) ? bcount[t] : 0;
    s[t] = v0;
    __syncthreads();
    for (int off = 1; off < 1024; off <<= 1) {
        int v = (t >= off) ? s[t - off] : 0;
        __syncthreads();
        s[t] += v;
        __syncthreads();
    }
    if (t < NB) {
        boffs[t + 1] = s[t];
        bcursor[t] = s[t] - v0;
    }
    if (t == 0) boffs[0] = 0;
}

__global__ void partition_kernel(const int* __restrict__ ei, int* __restrict__ bcursor,
                                 int* __restrict__ epart, int E, int NB) {
    __shared__ int lh[MAXNB];
    for (int j = threadIdx.x; j < NB; j += 256) lh[j] = 0;
    __syncthreads();
    int base = blockIdx.x * PCHUNK;
    int end = min(E, base + PCHUNK);
    for (int i = base + threadIdx.x; i < end; i += 256)
        atomicAdd(&lh[ei[E + i] >> BSH], 1);
    __syncthreads();
    for (int j = threadIdx.x; j < NB; j += 256) {
        int c = lh[j];
        lh[j] = c ? atomicAdd(&bcursor[j], c) : 0;
    }
    __syncthreads();
    for (int i = base + threadIdx.x; i < end; i += 256) {
        int dst = ei[E + i];
        int src = ei[i];
        int slot = atomicAdd(&lh[dst >> BSH], 1);
        epart[slot] = (src << BSH) | (dst & (BSZ - 1));
    }
}

// finalize: per-wave sub-histograms; node n gets deg+1 slots, slot 0 = self.
__global__ void finalize_kernel(const int* __restrict__ epart, const int* __restrict__ boffs,
                                int* __restrict__ offs, int* __restrict__ ssrc, int N,
                                int S /* = E + N, tail pad start */) {
    __shared__ int deg4[4][BSZ];
    __shared__ int pos[BSZ];
    __shared__ int cur4[4][BSZ];
    int b = blockIdx.x;
    int t = threadIdx.x;
    int w = t >> 6;
    int n0 = b << BSH;
    int r0 = boffs[b], r1 = boffs[b + 1];
    if (b == 0 && t < 128) ssrc[S + t] = 0;
    ((int*)deg4)[t] = 0;
    ((int*)deg4)[t + 256] = 0;
    __syncthreads();
    for (int e = r0 + t; e < r1; e += 256)
        atomicAdd(&deg4[w][epart[e] & (BSZ - 1)], 1);
    __syncthreads();
    int d0 = 0, d1 = 0, d2 = 0, sum = 0;
    if (t < BSZ) {
        d0 = deg4[0][t]; d1 = deg4[1][t]; d2 = deg4[2][t];
        sum = d0 + d1 + d2 + deg4[3][t];
        pos[t] = sum;
    }
    __syncthreads();
    for (int off = 1; off < BSZ; off <<= 1) {
        int v = (t < BSZ && t >= off) ? pos[t - off] : 0;
        __syncthreads();
        if (t < BSZ) pos[t] += v;
        __syncthreads();
    }
    if (t < BSZ) {
        int node = n0 + t;
        int base = r0 + n0 + (pos[t] - sum) + t;   // edges + self-slots before node
        if (node < N) {
            offs[node] = base;
            ssrc[base] = node;                     // self-loop at slot 0
        }
        cur4[0][t] = base + 1;
        cur4[1][t] = base + 1 + d0;
        cur4[2][t] = base + 1 + d0 + d1;
        cur4[3][t] = base + 1 + d0 + d1 + d2;
    }
    __syncthreads();
    for (int e = r0 + t; e < r1; e += 256) {
        int v = epart[e];
        int s = atomicAdd(&cur4[w][v & (BSZ - 1)], 1);
        ssrc[s] = v >> BSH;
    }
}

// ---------------- DPP cross-lane add (VALU pipe; compiler handles hazards) --
template <int CTRL>
__device__ __forceinline__ float dpp_add(float v) {
    union { float f; int i; } u, r;
    u.f = v;
    r.i = __builtin_amdgcn_update_dpp(0, u.i, CTRL, 0xF, 0xF, true);
    return v + r.f;
}

// ---------------- GATv2 layer: 8 edges per wave iteration, pipelined --------
// R17 lesson: the tail-slot index CLAMP to `wid` matters — it redirects
// masked gathers to the L1-hot own row. Removing it (R17) cost +7us/gat via
// ~0.7M extra scattered row-reads. This is the R15-measured 63.5us body with
// hoisted bounds (e1a/e1b).
template <int L>
__global__ void gat_kernel(const float* __restrict__ xl, const float* __restrict__ xr,
                           const int* __restrict__ offs, const int* __restrict__ ssrc,
                           const float* __restrict__ att, const float* __restrict__ bias,
                           const float* __restrict__ linW, const float* __restrict__ linb,
                           float* __restrict__ out, int N) {
    int wid = blockIdx.x * 4 + (threadIdx.x >> 6);
    int lane = threadIdx.x & 63;
    if (wid >= N) return;
    int grp = lane >> 4;          // edge slot within the 4-wide half-batch
    int li = lane & 15;           // float4 channel slot
    unsigned cb = (unsigned)li << 2;

    const float LOG2E = 1.4426950408889634f;
    float4 att4 = *(const float4*)(att + cb);
    att4.x *= LOG2E; att4.y *= LOG2E; att4.z *= LOG2E; att4.w *= LOG2E;
    float4 bias4 = *(const float4*)(bias + cb);
    unsigned rb = (unsigned)wid << 6;
    float4 xr4 = *(const float4*)(xr + rb + cb);

    int e0 = offs[wid], e1 = offs[wid + 1];
    int e1a = e1 - grp;           // t+grp < e1    <=>  t < e1a
    int e1b = e1 - 4 - grp;       // t+4+grp < e1  <=>  t < e1b

    float s = 0.f;
    float4 acc = {0.f, 0.f, 0.f, 0.f};

    // prologue (ssrc padded -> unconditional loads OK; clamp to hot own-row)
    unsigned sA = (unsigned)ssrc[e0 + grp];
    unsigned sB = (unsigned)ssrc[e0 + 4 + grp];
    sA = (e0 < e1a) ? sA : (unsigned)wid;
    sB = (e0 < e1b) ? sB : (unsigned)wid;

    for (int t = e0; t < e1; t += 8) {
        float4 a = *(const float4*)(xl + (sA << 6) + cb);
        float4 b = *(const float4*)(xl + (sB << 6) + cb);
        int tn = t + 8;
        unsigned nA = (unsigned)ssrc[tn + grp];
        unsigned nB = (unsigned)ssrc[tn + 4 + grp];
        nA = (tn < e1a) ? nA : (unsigned)wid;
        nB = (tn < e1b) ? nB : (unsigned)wid;
        bool vA = t < e1a;
        bool vB = t < e1b;

        float ux = a.x + xr4.x; ux = fmaxf(ux, 0.2f * ux);
        float uy = a.y + xr4.y; uy = fmaxf(uy, 0.2f * uy);
        float uz = a.z + xr4.z; uz = fmaxf(uz, 0.2f * uz);
        float uw = a.w + xr4.w; uw = fmaxf(uw, 0.2f * uw);
        float pa = att4.x * ux + att4.y * uy + att4.z * uz + att4.w * uw;
        pa = dpp_add<0xB1>(pa);
        pa = dpp_add<0x4E>(pa);
        if (L == 2) {
            pa = dpp_add<0x141>(pa);
            pa = dpp_add<0x140>(pa);
        }
        float pA = exp2f(pa);
        pA = vA ? pA : 0.f;
        s += pA;
        acc.x += pA * a.x; acc.y += pA * a.y; acc.z += pA * a.z; acc.w += pA * a.w;

        float vx = b.x + xr4.x; vx = fmaxf(vx, 0.2f * vx);
        float vy = b.y + xr4.y; vy = fmaxf(vy, 0.2f * vy);
        float vz = b.z + xr4.z; vz = fmaxf(vz, 0.2f * vz);
        float vw = b.w + xr4.w; vw = fmaxf(vw, 0.2f * vw);
        float pb = att4.x * vx + att4.y * vy + att4.z * vz + att4.w * vw;
        pb = dpp_add<0xB1>(pb);
        pb = dpp_add<0x4E>(pb);
        if (L == 2) {
            pb = dpp_add<0x141>(pb);
            pb = dpp_add<0x140>(pb);
        }
        float pB = exp2f(pb);
        pB = vB ? pB : 0.f;
        s += pB;
        acc.x += pB * b.x; acc.y += pB * b.y; acc.z += pB * b.z; acc.w += pB * b.w;

        sA = nA; sB = nB;
    }

    // combine the 4 edge groups (once per node)
    s += __shfl_xor(s, 16); s += __shfl_xor(s, 32);
    acc.x += __shfl_xor(acc.x, 16); acc.x += __shfl_xor(acc.x, 32);
    acc.y += __shfl_xor(acc.y, 16); acc.y += __shfl_xor(acc.y, 32);
    acc.z += __shfl_xor(acc.z, 16); acc.z += __shfl_xor(acc.z, 32);
    acc.w += __shfl_xor(acc.w, 16); acc.w += __shfl_xor(acc.w, 32);

    float inv = 1.f / (s + 1e-16f);
    if (L == 1) {
        float4 val;
        val.x = acc.x * inv + bias4.x;
        val.y = acc.y * inv + bias4.y;
        val.z = acc.z * inv + bias4.z;
        val.w = acc.w * inv + bias4.w;
        val.x = (val.x > 0.f) ? val.x : (__expf(val.x) - 1.f);
        val.y = (val.y > 0.f) ? val.y : (__expf(val.y) - 1.f);
        val.z = (val.z > 0.f) ? val.z : (__expf(val.z) - 1.f);
        val.w = (val.w > 0.f) ? val.w : (__expf(val.w) - 1.f);
        if (grp == 0) *(float4*)(out + rb + cb) = val;
    } else {
        float4 lw = *(const float4*)(linW + cb);
        float r = (acc.x * inv + bias4.x) * lw.x + (acc.y * inv + bias4.y) * lw.y +
                  (acc.z * inv + bias4.z) * lw.z + (acc.w * inv + bias4.w) * lw.w;
        r = dpp_add<0xB1>(r);
        r = dpp_add<0x4E>(r);
        r = dpp_add<0x141>(r);
        r = dpp_add<0x140>(r);
        if (lane == 0) out[wid] = r + linb[0];
    }
}

extern "C" void kernel_launch(void* const* d_in, const int* in_sizes, int n_in,
                              void* d_out, int out_size, void* d_ws, size_t ws_size,
                              hipStream_t stream) {
    const int* x = (const int*)d_in[0];
    const int* ei = (const int*)d_in[1];          // int32 marshalled
    const float* birth_tab = (const float*)d_in[2];
    const float* gender_tab = (const float*)d_in[3];
    const float* symp_tab = (const float*)d_in[4];
    const float* Wl1 = (const float*)d_in[5];
    const float* bl1 = (const float*)d_in[6];
    const float* Wr1 = (const float*)d_in[7];
    const float* br1 = (const float*)d_in[8];
    const float* att1 = (const float*)d_in[9];
    const float* bias1 = (const float*)d_in[10];
    const float* Wl2 = (const float*)d_in[11];
    const float* bl2 = (const float*)d_in[12];
    const float* Wr2 = (const float*)d_in[13];
    const float* br2 = (const float*)d_in[14];
    const float* att2 = (const float*)d_in[15];
    const float* bias2 = (const float*)d_in[16];
    const float* linW = (const float*)d_in[17];
    const float* linb = (const float*)d_in[18];
    float* outp = (float*)d_out;

    int N = in_sizes[0] / XCOLS;   // 100000
    int E = in_sizes[1] / 2;       // 1600000
    int NB = (N + BSZ - 1) >> BSH; // 782

    char* p = (char*)d_ws;
    auto alloc = [&](size_t bytes) {
        void* r = (void*)p;
        p += (bytes + 255) & ~(size_t)255;
        return r;
    };
    float* h0 = (float*)alloc((size_t)N * EMB * 4);
    float* bufA = (float*)alloc((size_t)N * EMB * 4);
    float* bufB = (float*)alloc((size_t)N * EMB * 4);
    int* bcount = (int*)alloc(MAXNB * 4);
    int* boffs = (int*)alloc((MAXNB + 1) * 4);
    int* bcursor = (int*)alloc(MAXNB * 4);
    int* offs = (int*)alloc((size_t)(N + 1) * 4);
    int* epart = (int*)alloc((size_t)E * 4);
    int* ssrc = (int*)alloc((size_t)(E + N + 128) * 4);  // edges + selfs + pad
    float* tL = (float*)alloc((size_t)TROWS * EMB * 4);
    float* tR = (float*)alloc((size_t)TROWS * EMB * 4);

    int ngrp = (N + 3) / 4;

    hipMemsetAsync(bcount, 0, MAXNB * 4, stream);
    // bincount (+ fused table transform)
    bincount_kernel<<<512, 256, 0, stream>>>(ei, bcount, offs, E, NB, N,
                                             birth_tab, gender_tab, symp_tab,
                                             Wl1, Wr1, tL, tR);
    bscan_kernel<<<1, 1024, 0, stream>>>(bcount, boffs, bcursor, NB);
    partition_kernel<<<(E + PCHUNK - 1) / PCHUNK, 256, 0, stream>>>(ei, bcursor, epart, E, NB);
    finalize_kernel<<<NB, 256, 0, stream>>>(epart, boffs, offs, ssrc, N, E + N);

    // node pipeline
    embedgemm_kernel<<<ngrp, 256, 0, stream>>>(x, tL, tR, bl1, br1, bufA, bufB, N);
    gat_kernel<1><<<ngrp, 256, 0, stream>>>(bufA, bufB, offs, ssrc, att1, bias1,
                                            nullptr, nullptr, h0, N);
    gemm_dual_kernel<<<768, 256, 0, stream>>>(h0, Wl2, bl2, Wr2, br2, bufA, bufB, N);
    gat_kernel<2><<<ngrp, 256, 0, stream>>>(bufA, bufB, offs, ssrc, att2, bias2,
                                            linW, linb, outp, N);
}

// Round 19
// 248.771 us; speedup vs baseline: 1.0834x; 1.0341x over previous
//
#include <hip/hip_runtime.h>
#include <hip/hip_bf16.h>

#define EMB 64
#define XCOLS 20
#define NSYMP 15
#define BSH 7
#define BSZ 128          // nodes per bucket (1<<BSH)
#define MAXNB 1024       // supports N <= 131072
#define PCHUNK 4096
#define TROWS 51         // 4 birth + 2 gender + 45 symp rows

typedef float sf16 __attribute__((ext_vector_type(16)));

// ---------------- bincount + fused table transform ----------------
__global__ void bincount_kernel(const int* __restrict__ ei, int* __restrict__ bcount,
                                int* __restrict__ offs, int E, int NB, int N,
                                const float* __restrict__ bt,
                                const float* __restrict__ gt,
                                const float* __restrict__ st,
                                const float* __restrict__ Wl,
                                const float* __restrict__ Wr,
                                float* __restrict__ tL, float* __restrict__ tR) {
    __shared__ int lh[MAXNB];
    __shared__ float row[EMB];
    for (int j = threadIdx.x; j < NB; j += 256) lh[j] = 0;
    int r = blockIdx.x;
    if (r < TROWS && threadIdx.x < EMB) {
        const float* src = (r < 4) ? (bt + r * EMB)
                         : (r < 6) ? (gt + (r - 4) * EMB)
                                   : (st + (r - 6) * EMB);
        row[threadIdx.x] = src[threadIdx.x];
    }
    __syncthreads();
    if (r < TROWS && threadIdx.x < EMB) {
        int d = threadIdx.x;
        float aL = 0.f, aR = 0.f;
#pragma unroll
        for (int k = 0; k < EMB; ++k) {
            float h = row[k];
            aL = fmaf(h, Wl[k * EMB + d], aL);
            aR = fmaf(h, Wr[k * EMB + d], aR);
        }
        tL[r * EMB + d] = aL;
        tR[r * EMB + d] = aR;
    }
    for (int i = blockIdx.x * 256 + threadIdx.x; i < E; i += gridDim.x * 256)
        atomicAdd(&lh[ei[E + i] >> BSH], 1);
    __syncthreads();
    for (int j = threadIdx.x; j < NB; j += 256)
        if (lh[j]) atomicAdd(&bcount[j], lh[j]);
    if (blockIdx.x == 0 && threadIdx.x == 0) offs[N] = E + N;   // slots incl. selfs
}

// ---------------- CSR bucket scan ----------------
__global__ void bscan_kernel(const int* __restrict__ bcount, int* __restrict__ boffs,
                             int* __restrict__ bcursor, int NB) {
    __shared__ int s[1024];
    int t = threadIdx.x;
    int v0 = (t < NB) ? bcount[t] : 0;
    s[t] = v0;
    __syncthreads();
    for (int off = 1; off < 1024; off <<= 1) {
        int v = (t >= off) ? s[t - off] : 0;
        __syncthreads();
        s[t] += v;
        __syncthreads();
    }
    if (t < NB) {
        boffs[t + 1] = s[t];
        bcursor[t] = s[t] - v0;
    }
    if (t == 0) boffs[0] = 0;
}

// ---------------- partition + fused embedgemm (block-role split) ----------
// Blocks [0,PB): radix-partition edges into bucket-major epart.
// Blocks [PB,PB+ngrp): embed+GEMM1 via pre-transformed tables (independent
// work, hidden under the partition pass instead of serialized after it).
__global__ void partition_embed_kernel(const int* __restrict__ ei, int* __restrict__ bcursor,
                                       int* __restrict__ epart, int E, int NB, int PB,
                                       const int* __restrict__ x,
                                       const float* __restrict__ tL,
                                       const float* __restrict__ tR,
                                       const float* __restrict__ bl,
                                       const float* __restrict__ br,
                                       float* __restrict__ outL, float* __restrict__ outR,
                                       int N) {
    __shared__ int lh[MAXNB];      // partition role (4 KB)
    __shared__ int xs[4 * XCOLS];  // embed role (320 B)
    if (blockIdx.x >= PB) {
        // ---- embedgemm role ----
        int bid = blockIdx.x - PB;
        int node = bid * 4 + (threadIdx.x >> 6);
        int d = threadIdx.x & 63;
        if (threadIdx.x < 4 * XCOLS) {
            int n2 = bid * 4 + threadIdx.x / XCOLS;
            xs[threadIdx.x] = (n2 < N) ? x[(size_t)bid * 4 * XCOLS + threadIdx.x] : 0;
        }
        __syncthreads();
        if (node >= N) return;
        const int* xr = &xs[(threadIdx.x >> 6) * XCOLS];
        int rbi = xr[1] + 2 * xr[2] + 3 * xr[3];   // birth row 0..3
        int rg = 4 + xr[4];                        // gender row 4..5
        float fL = 0.f, fR = 0.f;
#pragma unroll
        for (int j = 0; j < NSYMP; ++j) {
            int row = 6 + j * 3 + xr[5 + j];
            fL += tL[row * EMB + d];
            fR += tR[row * EMB + d];
        }
        float aL = (tL[rbi * EMB + d] + tL[rg * EMB + d] + fL * (1.f / 15.f)) * (1.f / 3.f) + bl[d];
        float aR = (tR[rbi * EMB + d] + tR[rg * EMB + d] + fR * (1.f / 15.f)) * (1.f / 3.f) + br[d];
        outL[node * EMB + d] = aL;
        outR[node * EMB + d] = aR;
        return;
    }
    // ---- partition role ----
    for (int j = threadIdx.x; j < NB; j += 256) lh[j] = 0;
    __syncthreads();
    int base = blockIdx.x * PCHUNK;
    int end = min(E, base + PCHUNK);
    for (int i = base + threadIdx.x; i < end; i += 256)
        atomicAdd(&lh[ei[E + i] >> BSH], 1);
    __syncthreads();
    for (int j = threadIdx.x; j < NB; j += 256) {
        int c = lh[j];
        lh[j] = c ? atomicAdd(&bcursor[j], c) : 0;
    }
    __syncthreads();
    for (int i = base + threadIdx.x; i < end; i += 256) {
        int dst = ei[E + i];
        int src = ei[i];
        int slot = atomicAdd(&lh[dst >> BSH], 1);
        epart[slot] = (src << BSH) | (dst & (BSZ - 1));
    }
}

// ---------------- dual GEMM v8: scalar-cache h broadcast + register weights --
__global__ __launch_bounds__(256, 3)
void gemm_dual_kernel(const float* __restrict__ h,
                      const float* __restrict__ Wl, const float* __restrict__ bl,
                      const float* __restrict__ Wr, const float* __restrict__ br,
                      float* __restrict__ outL, float* __restrict__ outR, int N) {
    int lane = threadIdx.x & 63;
    int wv = threadIdx.x >> 6;
    float wl[EMB], wr[EMB];
#pragma unroll
    for (int k = 0; k < EMB; ++k) {
        wl[k] = Wl[k * EMB + lane];
        wr[k] = Wr[k * EMB + lane];
    }
    float blv = bl[lane], brv = br[lane];
    int stride = gridDim.x * 4;
    for (int node = blockIdx.x * 4 + wv; node < N; node += stride) {
        int un = __builtin_amdgcn_readfirstlane(node);
        const float* hrow = h + (size_t)un * EMB;
        sf16 va, vb, vc, vd;
        asm volatile("s_load_dwordx16 %0, %1, 0x0"  : "=s"(va) : "s"(hrow));
        asm volatile("s_load_dwordx16 %0, %1, 0x40" : "=s"(vb) : "s"(hrow));
        asm volatile("s_load_dwordx16 %0, %1, 0x80" : "=s"(vc) : "s"(hrow));
        asm volatile("s_load_dwordx16 %0, %1, 0xc0" : "=s"(vd) : "s"(hrow));
        asm volatile("s_waitcnt lgkmcnt(0)" ::: "memory");
        __builtin_amdgcn_sched_barrier(0);
        float l0 = blv, l1 = 0.f, r0 = brv, r1 = 0.f;
#pragma unroll
        for (int k = 0; k < 16; ++k) {
            l0 = fmaf(va[k], wl[k], l0);
            r0 = fmaf(va[k], wr[k], r0);
            l1 = fmaf(vb[k], wl[16 + k], l1);
            r1 = fmaf(vb[k], wr[16 + k], r1);
            l0 = fmaf(vc[k], wl[32 + k], l0);
            r0 = fmaf(vc[k], wr[32 + k], r0);
            l1 = fmaf(vd[k], wl[48 + k], l1);
            r1 = fmaf(vd[k], wr[48 + k], r1);
        }
        outL[(size_t)node * EMB + lane] = l0 + l1;
        outR[(size_t)node * EMB + lane] = r0 + r1;
    }
}

// finalize: per-wave sub-histograms; node n gets deg+1 slots, slot 0 = self.
__global__ void finalize_kernel(const int* __restrict__ epart, const int* __restrict__ boffs,
                                int* __restrict__ offs, int* __restrict__ ssrc, int N,
                                int S /* = E + N, tail pad start */) {
    __shared__ int deg4[4][BSZ];
    __shared__ int pos[BSZ];
    __shared__ int cur4[4][BSZ];
    int b = blockIdx.x;
    int t = threadIdx.x;
    int w = t >> 6;
    int n0 = b << BSH;
    int r0 = boffs[b], r1 = boffs[b + 1];
    if (b == 0 && t < 128) ssrc[S + t] = 0;
    ((int*)deg4)[t] = 0;
    ((int*)deg4)[t + 256] = 0;
    __syncthreads();
    for (int e = r0 + t; e < r1; e += 256)
        atomicAdd(&deg4[w][epart[e] & (BSZ - 1)], 1);
    __syncthreads();
    int d0 = 0, d1 = 0, d2 = 0, sum = 0;
    if (t < BSZ) {
        d0 = deg4[0][t]; d1 = deg4[1][t]; d2 = deg4[2][t];
        sum = d0 + d1 + d2 + deg4[3][t];
        pos[t] = sum;
    }
    __syncthreads();
    for (int off = 1; off < BSZ; off <<= 1) {
        int v = (t < BSZ && t >= off) ? pos[t - off] : 0;
        __syncthreads();
        if (t < BSZ) pos[t] += v;
        __syncthreads();
    }
    if (t < BSZ) {
        int node = n0 + t;
        int base = r0 + n0 + (pos[t] - sum) + t;   // edges + self-slots before node
        if (node < N) {
            offs[node] = base;
            ssrc[base] = node;                     // self-loop at slot 0
        }
        cur4[0][t] = base + 1;
        cur4[1][t] = base + 1 + d0;
        cur4[2][t] = base + 1 + d0 + d1;
        cur4[3][t] = base + 1 + d0 + d1 + d2;
    }
    __syncthreads();
    for (int e = r0 + t; e < r1; e += 256) {
        int v = epart[e];
        int s = atomicAdd(&cur4[w][v & (BSZ - 1)], 1);
        ssrc[s] = v >> BSH;
    }
}

// ---------------- DPP cross-lane add (VALU pipe; compiler handles hazards) --
template <int CTRL>
__device__ __forceinline__ float dpp_add(float v) {
    union { float f; int i; } u, r;
    u.f = v;
    r.i = __builtin_amdgcn_update_dpp(0, u.i, CTRL, 0xF, 0xF, true);
    return v + r.f;
}

// ---------------- GATv2 layer: 8 edges per wave iteration, pipelined --------
// R17 lesson: the tail-slot index CLAMP to `wid` matters — it redirects
// masked gathers to the L1-hot own row. This is the R15-measured 63.5us body.
template <int L>
__global__ void gat_kernel(const float* __restrict__ xl, const float* __restrict__ xr,
                           const int* __restrict__ offs, const int* __restrict__ ssrc,
                           const float* __restrict__ att, const float* __restrict__ bias,
                           const float* __restrict__ linW, const float* __restrict__ linb,
                           float* __restrict__ out, int N) {
    int wid = blockIdx.x * 4 + (threadIdx.x >> 6);
    int lane = threadIdx.x & 63;
    if (wid >= N) return;
    int grp = lane >> 4;          // edge slot within the 4-wide half-batch
    int li = lane & 15;           // float4 channel slot
    unsigned cb = (unsigned)li << 2;

    const float LOG2E = 1.4426950408889634f;
    float4 att4 = *(const float4*)(att + cb);
    att4.x *= LOG2E; att4.y *= LOG2E; att4.z *= LOG2E; att4.w *= LOG2E;
    float4 bias4 = *(const float4*)(bias + cb);
    unsigned rb = (unsigned)wid << 6;
    float4 xr4 = *(const float4*)(xr + rb + cb);

    int e0 = offs[wid], e1 = offs[wid + 1];
    int e1a = e1 - grp;           // t+grp < e1    <=>  t < e1a
    int e1b = e1 - 4 - grp;       // t+4+grp < e1  <=>  t < e1b

    float s = 0.f;
    float4 acc = {0.f, 0.f, 0.f, 0.f};

    // prologue (ssrc padded -> unconditional loads OK; clamp to hot own-row)
    unsigned sA = (unsigned)ssrc[e0 + grp];
    unsigned sB = (unsigned)ssrc[e0 + 4 + grp];
    sA = (e0 < e1a) ? sA : (unsigned)wid;
    sB = (e0 < e1b) ? sB : (unsigned)wid;

    for (int t = e0; t < e1; t += 8) {
        float4 a = *(const float4*)(xl + (sA << 6) + cb);
        float4 b = *(const float4*)(xl + (sB << 6) + cb);
        int tn = t + 8;
        unsigned nA = (unsigned)ssrc[tn + grp];
        unsigned nB = (unsigned)ssrc[tn + 4 + grp];
        nA = (tn < e1a) ? nA : (unsigned)wid;
        nB = (tn < e1b) ? nB : (unsigned)wid;
        bool vA = t < e1a;
        bool vB = t < e1b;

        float ux = a.x + xr4.x; ux = fmaxf(ux, 0.2f * ux);
        float uy = a.y + xr4.y; uy = fmaxf(uy, 0.2f * uy);
        float uz = a.z + xr4.z; uz = fmaxf(uz, 0.2f * uz);
        float uw = a.w + xr4.w; uw = fmaxf(uw, 0.2f * uw);
        float pa = att4.x * ux + att4.y * uy + att4.z * uz + att4.w * uw;
        pa = dpp_add<0xB1>(pa);
        pa = dpp_add<0x4E>(pa);
        if (L == 2) {
            pa = dpp_add<0x141>(pa);
            pa = dpp_add<0x140>(pa);
        }
        float pA = exp2f(pa);
        pA = vA ? pA : 0.f;
        s += pA;
        acc.x += pA * a.x; acc.y += pA * a.y; acc.z += pA * a.z; acc.w += pA * a.w;

        float vx = b.x + xr4.x; vx = fmaxf(vx, 0.2f * vx);
        float vy = b.y + xr4.y; vy = fmaxf(vy, 0.2f * vy);
        float vz = b.z + xr4.z; vz = fmaxf(vz, 0.2f * vz);
        float vw = b.w + xr4.w; vw = fmaxf(vw, 0.2f * vw);
        float pb = att4.x * vx + att4.y * vy + att4.z * vz + att4.w * vw;
        pb = dpp_add<0xB1>(pb);
        pb = dpp_add<0x4E>(pb);
        if (L == 2) {
            pb = dpp_add<0x141>(pb);
            pb = dpp_add<0x140>(pb);
        }
        float pB = exp2f(pb);
        pB = vB ? pB : 0.f;
        s += pB;
        acc.x += pB * b.x; acc.y += pB * b.y; acc.z += pB * b.z; acc.w += pB * b.w;

        sA = nA; sB = nB;
    }

    // combine the 4 edge groups (once per node)
    s += __shfl_xor(s, 16); s += __shfl_xor(s, 32);
    acc.x += __shfl_xor(acc.x, 16); acc.x += __shfl_xor(acc.x, 32);
    acc.y += __shfl_xor(acc.y, 16); acc.y += __shfl_xor(acc.y, 32);
    acc.z += __shfl_xor(acc.z, 16); acc.z += __shfl_xor(acc.z, 32);
    acc.w += __shfl_xor(acc.w, 16); acc.w += __shfl_xor(acc.w, 32);

    float inv = 1.f / (s + 1e-16f);
    if (L == 1) {
        float4 val;
        val.x = acc.x * inv + bias4.x;
        val.y = acc.y * inv + bias4.y;
        val.z = acc.z * inv + bias4.z;
        val.w = acc.w * inv + bias4.w;
        val.x = (val.x > 0.f) ? val.x : (__expf(val.x) - 1.f);
        val.y = (val.y > 0.f) ? val.y : (__expf(val.y) - 1.f);
        val.z = (val.z > 0.f) ? val.z : (__expf(val.z) - 1.f);
        val.w = (val.w > 0.f) ? val.w : (__expf(val.w) - 1.f);
        if (grp == 0) *(float4*)(out + rb + cb) = val;
    } else {
        float4 lw = *(const float4*)(linW + cb);
        float r = (acc.x * inv + bias4.x) * lw.x + (acc.y * inv + bias4.y) * lw.y +
                  (acc.z * inv + bias4.z) * lw.z + (acc.w * inv + bias4.w) * lw.w;
        r = dpp_add<0xB1>(r);
        r = dpp_add<0x4E>(r);
        r = dpp_add<0x141>(r);
        r = dpp_add<0x140>(r);
        if (lane == 0) out[wid] = r + linb[0];
    }
}

extern "C" void kernel_launch(void* const* d_in, const int* in_sizes, int n_in,
                              void* d_out, int out_size, void* d_ws, size_t ws_size,
                              hipStream_t stream) {
    const int* x = (const int*)d_in[0];
    const int* ei = (const int*)d_in[1];          // int32 marshalled
    const float* birth_tab = (const float*)d_in[2];
    const float* gender_tab = (const float*)d_in[3];
    const float* symp_tab = (const float*)d_in[4];
    const float* Wl1 = (const float*)d_in[5];
    const float* bl1 = (const float*)d_in[6];
    const float* Wr1 = (const float*)d_in[7];
    const float* br1 = (const float*)d_in[8];
    const float* att1 = (const float*)d_in[9];
    const float* bias1 = (const float*)d_in[10];
    const float* Wl2 = (const float*)d_in[11];
    const float* bl2 = (const float*)d_in[12];
    const float* Wr2 = (const float*)d_in[13];
    const float* br2 = (const float*)d_in[14];
    const float* att2 = (const float*)d_in[15];
    const float* bias2 = (const float*)d_in[16];
    const float* linW = (const float*)d_in[17];
    const float* linb = (const float*)d_in[18];
    float* outp = (float*)d_out;

    int N = in_sizes[0] / XCOLS;   // 100000
    int E = in_sizes[1] / 2;       // 1600000
    int NB = (N + BSZ - 1) >> BSH; // 782

    char* p = (char*)d_ws;
    auto alloc = [&](size_t bytes) {
        void* r = (void*)p;
        p += (bytes + 255) & ~(size_t)255;
        return r;
    };
    float* h0 = (float*)alloc((size_t)N * EMB * 4);
    float* bufA = (float*)alloc((size_t)N * EMB * 4);
    float* bufB = (float*)alloc((size_t)N * EMB * 4);
    int* bcount = (int*)alloc(MAXNB * 4);
    int* boffs = (int*)alloc((MAXNB + 1) * 4);
    int* bcursor = (int*)alloc(MAXNB * 4);
    int* offs = (int*)alloc((size_t)(N + 1) * 4);
    int* epart = (int*)alloc((size_t)E * 4);
    int* ssrc = (int*)alloc((size_t)(E + N + 128) * 4);  // edges + selfs + pad
    float* tL = (float*)alloc((size_t)TROWS * EMB * 4);
    float* tR = (float*)alloc((size_t)TROWS * EMB * 4);

    int ngrp = (N + 3) / 4;
    int PB = (E + PCHUNK - 1) / PCHUNK;

    hipMemsetAsync(bcount, 0, MAXNB * 4, stream);
    // bincount (+ fused table transform)
    bincount_kernel<<<512, 256, 0, stream>>>(ei, bcount, offs, E, NB, N,
                                             birth_tab, gender_tab, symp_tab,
                                             Wl1, Wr1, tL, tR);
    bscan_kernel<<<1, 1024, 0, stream>>>(bcount, boffs, bcursor, NB);
    // partition + embedgemm run concurrently (block-role split)
    partition_embed_kernel<<<PB + ngrp, 256, 0, stream>>>(ei, bcursor, epart, E, NB, PB,
                                                          x, tL, tR, bl1, br1,
                                                          bufA, bufB, N);
    finalize_kernel<<<NB, 256, 0, stream>>>(epart, boffs, offs, ssrc, N, E + N);

    // node pipeline
    gat_kernel<1><<<ngrp, 256, 0, stream>>>(bufA, bufB, offs, ssrc, att1, bias1,
                                            nullptr, nullptr, h0, N);
    gemm_dual_kernel<<<768, 256, 0, stream>>>(h0, Wl2, bl2, Wr2, br2, bufA, bufB, N);
    gat_kernel<2><<<ngrp, 256, 0, stream>>>(bufA, bufB, offs, ssrc, att2, bias2,
                                            linW, linb, outp, N);
}

// Round 20
// 248.190 us; speedup vs baseline: 1.0860x; 1.0023x over previous
//
#include <hip/hip_runtime.h>
#include <hip/hip_bf16.h>

#define EMB 64
#define XCOLS 20
#define NSYMP 15
#define BSH 7
#define BSZ 128          // nodes per bucket (1<<BSH)
#define MAXNB 1024       // supports N <= 131072
#define PCHUNK 16384     // R20: 4096->16384. 98 partition blocks: 4x shallower
                         // bcursor atomic queues + 21-edge (84B) scatter runs
                         // (write amp 3x->1.5x). Underfill is covered by the
                         // fused embed blocks (R19).
#define TROWS 51         // 4 birth + 2 gender + 45 symp rows

typedef float sf16 __attribute__((ext_vector_type(16)));

// ---------------- bincount + fused table transform ----------------
__global__ void bincount_kernel(const int* __restrict__ ei, int* __restrict__ bcount,
                                int* __restrict__ offs, int E, int NB, int N,
                                const float* __restrict__ bt,
                                const float* __restrict__ gt,
                                const float* __restrict__ st,
                                const float* __restrict__ Wl,
                                const float* __restrict__ Wr,
                                float* __restrict__ tL, float* __restrict__ tR) {
    __shared__ int lh[MAXNB];
    __shared__ float row[EMB];
    for (int j = threadIdx.x; j < NB; j += 256) lh[j] = 0;
    int r = blockIdx.x;
    if (r < TROWS && threadIdx.x < EMB) {
        const float* src = (r < 4) ? (bt + r * EMB)
                         : (r < 6) ? (gt + (r - 4) * EMB)
                                   : (st + (r - 6) * EMB);
        row[threadIdx.x] = src[threadIdx.x];
    }
    __syncthreads();
    if (r < TROWS && threadIdx.x < EMB) {
        int d = threadIdx.x;
        float aL = 0.f, aR = 0.f;
#pragma unroll
        for (int k = 0; k < EMB; ++k) {
            float h = row[k];
            aL = fmaf(h, Wl[k * EMB + d], aL);
            aR = fmaf(h, Wr[k * EMB + d], aR);
        }
        tL[r * EMB + d] = aL;
        tR[r * EMB + d] = aR;
    }
    for (int i = blockIdx.x * 256 + threadIdx.x; i < E; i += gridDim.x * 256)
        atomicAdd(&lh[ei[E + i] >> BSH], 1);
    __syncthreads();
    for (int j = threadIdx.x; j < NB; j += 256)
        if (lh[j]) atomicAdd(&bcount[j], lh[j]);
    if (blockIdx.x == 0 && threadIdx.x == 0) offs[N] = E + N;   // slots incl. selfs
}

// ---------------- CSR bucket scan ----------------
__global__ void bscan_kernel(const int* __restrict__ bcount, int* __restrict__ boffs,
                             int* __restrict__ bcursor, int NB) {
    __shared__ int s[1024];
    int t = threadIdx.x;
    int v0 = (t < NB) ? bcount[t] : 0;
    s[t] = v0;
    __syncthreads();
    for (int off = 1; off < 1024; off <<= 1) {
        int v = (t >= off) ? s[t - off] : 0;
        __syncthreads();
        s[t] += v;
        __syncthreads();
    }
    if (t < NB) {
        boffs[t + 1] = s[t];
        bcursor[t] = s[t] - v0;
    }
    if (t == 0) boffs[0] = 0;
}

// ---------------- partition + fused embedgemm (block-role split) ----------
__global__ void partition_embed_kernel(const int* __restrict__ ei, int* __restrict__ bcursor,
                                       int* __restrict__ epart, int E, int NB, int PB,
                                       const int* __restrict__ x,
                                       const float* __restrict__ tL,
                                       const float* __restrict__ tR,
                                       const float* __restrict__ bl,
                                       const float* __restrict__ br,
                                       float* __restrict__ outL, float* __restrict__ outR,
                                       int N) {
    __shared__ int lh[MAXNB];      // partition role (4 KB)
    __shared__ int xs[4 * XCOLS];  // embed role (320 B)
    if (blockIdx.x >= PB) {
        // ---- embedgemm role ----
        int bid = blockIdx.x - PB;
        int node = bid * 4 + (threadIdx.x >> 6);
        int d = threadIdx.x & 63;
        if (threadIdx.x < 4 * XCOLS) {
            int n2 = bid * 4 + threadIdx.x / XCOLS;
            xs[threadIdx.x] = (n2 < N) ? x[(size_t)bid * 4 * XCOLS + threadIdx.x] : 0;
        }
        __syncthreads();
        if (node >= N) return;
        const int* xr = &xs[(threadIdx.x >> 6) * XCOLS];
        int rbi = xr[1] + 2 * xr[2] + 3 * xr[3];   // birth row 0..3
        int rg = 4 + xr[4];                        // gender row 4..5
        float fL = 0.f, fR = 0.f;
#pragma unroll
        for (int j = 0; j < NSYMP; ++j) {
            int row = 6 + j * 3 + xr[5 + j];
            fL += tL[row * EMB + d];
            fR += tR[row * EMB + d];
        }
        float aL = (tL[rbi * EMB + d] + tL[rg * EMB + d] + fL * (1.f / 15.f)) * (1.f / 3.f) + bl[d];
        float aR = (tR[rbi * EMB + d] + tR[rg * EMB + d] + fR * (1.f / 15.f)) * (1.f / 3.f) + br[d];
        outL[node * EMB + d] = aL;
        outR[node * EMB + d] = aR;
        return;
    }
    // ---- partition role ----
    for (int j = threadIdx.x; j < NB; j += 256) lh[j] = 0;
    __syncthreads();
    int base = blockIdx.x * PCHUNK;
    int end = min(E, base + PCHUNK);
    for (int i = base + threadIdx.x; i < end; i += 256)
        atomicAdd(&lh[ei[E + i] >> BSH], 1);
    __syncthreads();
    for (int j = threadIdx.x; j < NB; j += 256) {
        int c = lh[j];
        lh[j] = c ? atomicAdd(&bcursor[j], c) : 0;
    }
    __syncthreads();
    for (int i = base + threadIdx.x; i < end; i += 256) {
        int dst = ei[E + i];
        int src = ei[i];
        int slot = atomicAdd(&lh[dst >> BSH], 1);
        epart[slot] = (src << BSH) | (dst & (BSZ - 1));
    }
}

// ---------------- dual GEMM v8: scalar-cache h broadcast + register weights --
__global__ __launch_bounds__(256, 3)
void gemm_dual_kernel(const float* __restrict__ h,
                      const float* __restrict__ Wl, const float* __restrict__ bl,
                      const float* __restrict__ Wr, const float* __restrict__ br,
                      float* __restrict__ outL, float* __restrict__ outR, int N) {
    int lane = threadIdx.x & 63;
    int wv = threadIdx.x >> 6;
    float wl[EMB], wr[EMB];
#pragma unroll
    for (int k = 0; k < EMB; ++k) {
        wl[k] = Wl[k * EMB + lane];
        wr[k] = Wr[k * EMB + lane];
    }
    float blv = bl[lane], brv = br[lane];
    int stride = gridDim.x * 4;
    for (int node = blockIdx.x * 4 + wv; node < N; node += stride) {
        int un = __builtin_amdgcn_readfirstlane(node);
        const float* hrow = h + (size_t)un * EMB;
        sf16 va, vb, vc, vd;
        asm volatile("s_load_dwordx16 %0, %1, 0x0"  : "=s"(va) : "s"(hrow));
        asm volatile("s_load_dwordx16 %0, %1, 0x40" : "=s"(vb) : "s"(hrow));
        asm volatile("s_load_dwordx16 %0, %1, 0x80" : "=s"(vc) : "s"(hrow));
        asm volatile("s_load_dwordx16 %0, %1, 0xc0" : "=s"(vd) : "s"(hrow));
        asm volatile("s_waitcnt lgkmcnt(0)" ::: "memory");
        __builtin_amdgcn_sched_barrier(0);
        float l0 = blv, l1 = 0.f, r0 = brv, r1 = 0.f;
#pragma unroll
        for (int k = 0; k < 16; ++k) {
            l0 = fmaf(va[k], wl[k], l0);
            r0 = fmaf(va[k], wr[k], r0);
            l1 = fmaf(vb[k], wl[16 + k], l1);
            r1 = fmaf(vb[k], wr[16 + k], r1);
            l0 = fmaf(vc[k], wl[32 + k], l0);
            r0 = fmaf(vc[k], wr[32 + k], r0);
            l1 = fmaf(vd[k], wl[48 + k], l1);
            r1 = fmaf(vd[k], wr[48 + k], r1);
        }
        outL[(size_t)node * EMB + lane] = l0 + l1;
        outR[(size_t)node * EMB + lane] = r0 + r1;
    }
}

// finalize: per-wave sub-histograms; node n gets deg+1 slots, slot 0 = self.
__global__ void finalize_kernel(const int* __restrict__ epart, const int* __restrict__ boffs,
                                int* __restrict__ offs, int* __restrict__ ssrc, int N,
                                int S /* = E + N, tail pad start */) {
    __shared__ int deg4[4][BSZ];
    __shared__ int pos[BSZ];
    __shared__ int cur4[4][BSZ];
    int b = blockIdx.x;
    int t = threadIdx.x;
    int w = t >> 6;
    int n0 = b << BSH;
    int r0 = boffs[b], r1 = boffs[b + 1];
    if (b == 0 && t < 128) ssrc[S + t] = 0;
    ((int*)deg4)[t] = 0;
    ((int*)deg4)[t + 256] = 0;
    __syncthreads();
    for (int e = r0 + t; e < r1; e += 256)
        atomicAdd(&deg4[w][epart[e] & (BSZ - 1)], 1);
    __syncthreads();
    int d0 = 0, d1 = 0, d2 = 0, sum = 0;
    if (t < BSZ) {
        d0 = deg4[0][t]; d1 = deg4[1][t]; d2 = deg4[2][t];
        sum = d0 + d1 + d2 + deg4[3][t];
        pos[t] = sum;
    }
    __syncthreads();
    for (int off = 1; off < BSZ; off <<= 1) {
        int v = (t < BSZ && t >= off) ? pos[t - off] : 0;
        __syncthreads();
        if (t < BSZ) pos[t] += v;
        __syncthreads();
    }
    if (t < BSZ) {
        int node = n0 + t;
        int base = r0 + n0 + (pos[t] - sum) + t;   // edges + self-slots before node
        if (node < N) {
            offs[node] = base;
            ssrc[base] = node;                     // self-loop at slot 0
        }
        cur4[0][t] = base + 1;
        cur4[1][t] = base + 1 + d0;
        cur4[2][t] = base + 1 + d0 + d1;
        cur4[3][t] = base + 1 + d0 + d1 + d2;
    }
    __syncthreads();
    for (int e = r0 + t; e < r1; e += 256) {
        int v = epart[e];
        int s = atomicAdd(&cur4[w][v & (BSZ - 1)], 1);
        ssrc[s] = v >> BSH;
    }
}

// ---------------- DPP cross-lane add (VALU pipe; compiler handles hazards) --
template <int CTRL>
__device__ __forceinline__ float dpp_add(float v) {
    union { float f; int i; } u, r;
    u.f = v;
    r.i = __builtin_amdgcn_update_dpp(0, u.i, CTRL, 0xF, 0xF, true);
    return v + r.f;
}

// ---------------- GATv2 layer: 8 edges per wave iteration, pipelined --------
// R17 lesson: the tail-slot index CLAMP to `wid` matters — it redirects
// masked gathers to the L1-hot own row. This is the R15-measured 63.5us body.
template <int L>
__global__ void gat_kernel(const float* __restrict__ xl, const float* __restrict__ xr,
                           const int* __restrict__ offs, const int* __restrict__ ssrc,
                           const float* __restrict__ att, const float* __restrict__ bias,
                           const float* __restrict__ linW, const float* __restrict__ linb,
                           float* __restrict__ out, int N) {
    int wid = blockIdx.x * 4 + (threadIdx.x >> 6);
    int lane = threadIdx.x & 63;
    if (wid >= N) return;
    int grp = lane >> 4;          // edge slot within the 4-wide half-batch
    int li = lane & 15;           // float4 channel slot
    unsigned cb = (unsigned)li << 2;

    const float LOG2E = 1.4426950408889634f;
    float4 att4 = *(const float4*)(att + cb);
    att4.x *= LOG2E; att4.y *= LOG2E; att4.z *= LOG2E; att4.w *= LOG2E;
    float4 bias4 = *(const float4*)(bias + cb);
    unsigned rb = (unsigned)wid << 6;
    float4 xr4 = *(const float4*)(xr + rb + cb);

    int e0 = offs[wid], e1 = offs[wid + 1];
    int e1a = e1 - grp;           // t+grp < e1    <=>  t < e1a
    int e1b = e1 - 4 - grp;       // t+4+grp < e1  <=>  t < e1b

    float s = 0.f;
    float4 acc = {0.f, 0.f, 0.f, 0.f};

    // prologue (ssrc padded -> unconditional loads OK; clamp to hot own-row)
    unsigned sA = (unsigned)ssrc[e0 + grp];
    unsigned sB = (unsigned)ssrc[e0 + 4 + grp];
    sA = (e0 < e1a) ? sA : (unsigned)wid;
    sB = (e0 < e1b) ? sB : (unsigned)wid;

    for (int t = e0; t < e1; t += 8) {
        float4 a = *(const float4*)(xl + (sA << 6) + cb);
        float4 b = *(const float4*)(xl + (sB << 6) + cb);
        int tn = t + 8;
        unsigned nA = (unsigned)ssrc[tn + grp];
        unsigned nB = (unsigned)ssrc[tn + 4 + grp];
        nA = (tn < e1a) ? nA : (unsigned)wid;
        nB = (tn < e1b) ? nB : (unsigned)wid;
        bool vA = t < e1a;
        bool vB = t < e1b;

        float ux = a.x + xr4.x; ux = fmaxf(ux, 0.2f * ux);
        float uy = a.y + xr4.y; uy = fmaxf(uy, 0.2f * uy);
        float uz = a.z + xr4.z; uz = fmaxf(uz, 0.2f * uz);
        float uw = a.w + xr4.w; uw = fmaxf(uw, 0.2f * uw);
        float pa = att4.x * ux + att4.y * uy + att4.z * uz + att4.w * uw;
        pa = dpp_add<0xB1>(pa);
        pa = dpp_add<0x4E>(pa);
        if (L == 2) {
            pa = dpp_add<0x141>(pa);
            pa = dpp_add<0x140>(pa);
        }
        float pA = exp2f(pa);
        pA = vA ? pA : 0.f;
        s += pA;
        acc.x += pA * a.x; acc.y += pA * a.y; acc.z += pA * a.z; acc.w += pA * a.w;

        float vx = b.x + xr4.x; vx = fmaxf(vx, 0.2f * vx);
        float vy = b.y + xr4.y; vy = fmaxf(vy, 0.2f * vy);
        float vz = b.z + xr4.z; vz = fmaxf(vz, 0.2f * vz);
        float vw = b.w + xr4.w; vw = fmaxf(vw, 0.2f * vw);
        float pb = att4.x * vx + att4.y * vy + att4.z * vz + att4.w * vw;
        pb = dpp_add<0xB1>(pb);
        pb = dpp_add<0x4E>(pb);
        if (L == 2) {
            pb = dpp_add<0x141>(pb);
            pb = dpp_add<0x140>(pb);
        }
        float pB = exp2f(pb);
        pB = vB ? pB : 0.f;
        s += pB;
        acc.x += pB * b.x; acc.y += pB * b.y; acc.z += pB * b.z; acc.w += pB * b.w;

        sA = nA; sB = nB;
    }

    // combine the 4 edge groups (once per node)
    s += __shfl_xor(s, 16); s += __shfl_xor(s, 32);
    acc.x += __shfl_xor(acc.x, 16); acc.x += __shfl_xor(acc.x, 32);
    acc.y += __shfl_xor(acc.y, 16); acc.y += __shfl_xor(acc.y, 32);
    acc.z += __shfl_xor(acc.z, 16); acc.z += __shfl_xor(acc.z, 32);
    acc.w += __shfl_xor(acc.w, 16); acc.w += __shfl_xor(acc.w, 32);

    float inv = 1.f / (s + 1e-16f);
    if (L == 1) {
        float4 val;
        val.x = acc.x * inv + bias4.x;
        val.y = acc.y * inv + bias4.y;
        val.z = acc.z * inv + bias4.z;
        val.w = acc.w * inv + bias4.w;
        val.x = (val.x > 0.f) ? val.x : (__expf(val.x) - 1.f);
        val.y = (val.y > 0.f) ? val.y : (__expf(val.y) - 1.f);
        val.z = (val.z > 0.f) ? val.z : (__expf(val.z) - 1.f);
        val.w = (val.w > 0.f) ? val.w : (__expf(val.w) - 1.f);
        if (grp == 0) *(float4*)(out + rb + cb) = val;
    } else {
        float4 lw = *(const float4*)(linW + cb);
        float r = (acc.x * inv + bias4.x) * lw.x + (acc.y * inv + bias4.y) * lw.y +
                  (acc.z * inv + bias4.z) * lw.z + (acc.w * inv + bias4.w) * lw.w;
        r = dpp_add<0xB1>(r);
        r = dpp_add<0x4E>(r);
        r = dpp_add<0x141>(r);
        r = dpp_add<0x140>(r);
        if (lane == 0) out[wid] = r + linb[0];
    }
}

extern "C" void kernel_launch(void* const* d_in, const int* in_sizes, int n_in,
                              void* d_out, int out_size, void* d_ws, size_t ws_size,
                              hipStream_t stream) {
    const int* x = (const int*)d_in[0];
    const int* ei = (const int*)d_in[1];          // int32 marshalled
    const float* birth_tab = (const float*)d_in[2];
    const float* gender_tab = (const float*)d_in[3];
    const float* symp_tab = (const float*)d_in[4];
    const float* Wl1 = (const float*)d_in[5];
    const float* bl1 = (const float*)d_in[6];
    const float* Wr1 = (const float*)d_in[7];
    const float* br1 = (const float*)d_in[8];
    const float* att1 = (const float*)d_in[9];
    const float* bias1 = (const float*)d_in[10];
    const float* Wl2 = (const float*)d_in[11];
    const float* bl2 = (const float*)d_in[12];
    const float* Wr2 = (const float*)d_in[13];
    const float* br2 = (const float*)d_in[14];
    const float* att2 = (const float*)d_in[15];
    const float* bias2 = (const float*)d_in[16];
    const float* linW = (const float*)d_in[17];
    const float* linb = (const float*)d_in[18];
    float* outp = (float*)d_out;

    int N = in_sizes[0] / XCOLS;   // 100000
    int E = in_sizes[1] / 2;       // 1600000
    int NB = (N + BSZ - 1) >> BSH; // 782

    char* p = (char*)d_ws;
    auto alloc = [&](size_t bytes) {
        void* r = (void*)p;
        p += (bytes + 255) & ~(size_t)255;
        return r;
    };
    float* h0 = (float*)alloc((size_t)N * EMB * 4);
    float* bufA = (float*)alloc((size_t)N * EMB * 4);
    float* bufB = (float*)alloc((size_t)N * EMB * 4);
    int* bcount = (int*)alloc(MAXNB * 4);
    int* boffs = (int*)alloc((MAXNB + 1) * 4);
    int* bcursor = (int*)alloc(MAXNB * 4);
    int* offs = (int*)alloc((size_t)(N + 1) * 4);
    int* epart = (int*)alloc((size_t)E * 4);
    int* ssrc = (int*)alloc((size_t)(E + N + 128) * 4);  // edges + selfs + pad
    float* tL = (float*)alloc((size_t)TROWS * EMB * 4);
    float* tR = (float*)alloc((size_t)TROWS * EMB * 4);

    int ngrp = (N + 3) / 4;
    int PB = (E + PCHUNK - 1) / PCHUNK;   // 98

    hipMemsetAsync(bcount, 0, MAXNB * 4, stream);
    // bincount (+ fused table transform)
    bincount_kernel<<<512, 256, 0, stream>>>(ei, bcount, offs, E, NB, N,
                                             birth_tab, gender_tab, symp_tab,
                                             Wl1, Wr1, tL, tR);
    bscan_kernel<<<1, 1024, 0, stream>>>(bcount, boffs, bcursor, NB);
    // partition + embedgemm run concurrently (block-role split)
    partition_embed_kernel<<<PB + ngrp, 256, 0, stream>>>(ei, bcursor, epart, E, NB, PB,
                                                          x, tL, tR, bl1, br1,
                                                          bufA, bufB, N);
    finalize_kernel<<<NB, 256, 0, stream>>>(epart, boffs, offs, ssrc, N, E + N);

    // node pipeline
    gat_kernel<1><<<ngrp, 256, 0, stream>>>(bufA, bufB, offs, ssrc, att1, bias1,
                                            nullptr, nullptr, h0, N);
    gemm_dual_kernel<<<768, 256, 0, stream>>>(h0, Wl2, bl2, Wr2, br2, bufA, bufB, N);
    gat_kernel<2><<<ngrp, 256, 0, stream>>>(bufA, bufB, offs, ssrc, att2, bias2,
                                            linW, linb, outp, N);
}

// Round 21
// 233.024 us; speedup vs baseline: 1.1566x; 1.0651x over previous
//
#include <hip/hip_runtime.h>
#include <hip/hip_bf16.h>

#define EMB 64
#define XCOLS 20
#define NSYMP 15
#define BSH 7
#define BSZ 128          // nodes per bucket (1<<BSH)
#define MAXNB 1024       // supports N <= 131072
#define PCHUNK 4096      // R20 lesson: partition is straggler-bound; more blocks > shallower queues
#define TROWS 51         // 4 birth + 2 gender + 45 symp rows
#define CAP 2560         // fixed edge capacity per bucket (mu=2046, sigma=45 -> ~11 sigma margin)
#define SCAP (CAP + BSZ) // slot capacity per bucket incl. self-loops

typedef float sf16 __attribute__((ext_vector_type(16)));

// ---------------- table transform ----------------
__global__ void transform_kernel(const float* __restrict__ bt,
                                 const float* __restrict__ gt,
                                 const float* __restrict__ st,
                                 const float* __restrict__ Wl,
                                 const float* __restrict__ Wr,
                                 float* __restrict__ tL, float* __restrict__ tR) {
    __shared__ float row[EMB];
    int r = blockIdx.x;          // 0..50
    int d = threadIdx.x;         // 64 threads
    const float* src = (r < 4) ? (bt + r * EMB)
                     : (r < 6) ? (gt + (r - 4) * EMB)
                               : (st + (r - 6) * EMB);
    row[d] = src[d];
    __syncthreads();
    float aL = 0.f, aR = 0.f;
#pragma unroll
    for (int k = 0; k < EMB; ++k) {
        float h = row[k];
        aL = fmaf(h, Wl[k * EMB + d], aL);
        aR = fmaf(h, Wr[k * EMB + d], aR);
    }
    tL[r * EMB + d] = aL;
    tR[r * EMB + d] = aR;
}

// ---------------- partition + fused embedgemm (block-role split) ----------
// Fixed-capacity buckets: no bincount/bscan. Phase 2 reserves runs at
// bucket*CAP + atomicAdd(bcursor) (bcursor starts 0). Inter-bucket holes in
// epart/ssrc are fine: gat uses per-node [offs, eoffs) ranges only.
__global__ void partition_embed_kernel(const int* __restrict__ ei, int* __restrict__ bcursor,
                                       int* __restrict__ epart, int E, int NB, int PB,
                                       const int* __restrict__ x,
                                       const float* __restrict__ tL,
                                       const float* __restrict__ tR,
                                       const float* __restrict__ bl,
                                       const float* __restrict__ br,
                                       float* __restrict__ outL, float* __restrict__ outR,
                                       int N) {
    __shared__ int lh[MAXNB];      // partition role (4 KB)
    __shared__ int xs[4 * XCOLS];  // embed role (320 B)
    if (blockIdx.x >= PB) {
        // ---- embedgemm role ----
        int bid = blockIdx.x - PB;
        int node = bid * 4 + (threadIdx.x >> 6);
        int d = threadIdx.x & 63;
        if (threadIdx.x < 4 * XCOLS) {
            int n2 = bid * 4 + threadIdx.x / XCOLS;
            xs[threadIdx.x] = (n2 < N) ? x[(size_t)bid * 4 * XCOLS + threadIdx.x] : 0;
        }
        __syncthreads();
        if (node >= N) return;
        const int* xr = &xs[(threadIdx.x >> 6) * XCOLS];
        int rbi = xr[1] + 2 * xr[2] + 3 * xr[3];   // birth row 0..3
        int rg = 4 + xr[4];                        // gender row 4..5
        float fL = 0.f, fR = 0.f;
#pragma unroll
        for (int j = 0; j < NSYMP; ++j) {
            int row = 6 + j * 3 + xr[5 + j];
            fL += tL[row * EMB + d];
            fR += tR[row * EMB + d];
        }
        float aL = (tL[rbi * EMB + d] + tL[rg * EMB + d] + fL * (1.f / 15.f)) * (1.f / 3.f) + bl[d];
        float aR = (tR[rbi * EMB + d] + tR[rg * EMB + d] + fR * (1.f / 15.f)) * (1.f / 3.f) + br[d];
        outL[node * EMB + d] = aL;
        outR[node * EMB + d] = aR;
        return;
    }
    // ---- partition role ----
    for (int j = threadIdx.x; j < NB; j += 256) lh[j] = 0;
    __syncthreads();
    int base = blockIdx.x * PCHUNK;
    int end = min(E, base + PCHUNK);
    for (int i = base + threadIdx.x; i < end; i += 256)
        atomicAdd(&lh[ei[E + i] >> BSH], 1);
    __syncthreads();
    for (int j = threadIdx.x; j < NB; j += 256) {
        int c = lh[j];
        lh[j] = c ? (j * CAP + atomicAdd(&bcursor[j], c)) : 0;
    }
    __syncthreads();
    for (int i = base + threadIdx.x; i < end; i += 256) {
        int dst = ei[E + i];
        int src = ei[i];
        int slot = atomicAdd(&lh[dst >> BSH], 1);
        epart[slot] = (src << BSH) | (dst & (BSZ - 1));
    }
}

// ---------------- dual GEMM v8: scalar-cache h broadcast + register weights --
__global__ __launch_bounds__(256, 3)
void gemm_dual_kernel(const float* __restrict__ h,
                      const float* __restrict__ Wl, const float* __restrict__ bl,
                      const float* __restrict__ Wr, const float* __restrict__ br,
                      float* __restrict__ outL, float* __restrict__ outR, int N) {
    int lane = threadIdx.x & 63;
    int wv = threadIdx.x >> 6;
    float wl[EMB], wr[EMB];
#pragma unroll
    for (int k = 0; k < EMB; ++k) {
        wl[k] = Wl[k * EMB + lane];
        wr[k] = Wr[k * EMB + lane];
    }
    float blv = bl[lane], brv = br[lane];
    int stride = gridDim.x * 4;
    for (int node = blockIdx.x * 4 + wv; node < N; node += stride) {
        int un = __builtin_amdgcn_readfirstlane(node);
        const float* hrow = h + (size_t)un * EMB;
        sf16 va, vb, vc, vd;
        asm volatile("s_load_dwordx16 %0, %1, 0x0"  : "=s"(va) : "s"(hrow));
        asm volatile("s_load_dwordx16 %0, %1, 0x40" : "=s"(vb) : "s"(hrow));
        asm volatile("s_load_dwordx16 %0, %1, 0x80" : "=s"(vc) : "s"(hrow));
        asm volatile("s_load_dwordx16 %0, %1, 0xc0" : "=s"(vd) : "s"(hrow));
        asm volatile("s_waitcnt lgkmcnt(0)" ::: "memory");
        __builtin_amdgcn_sched_barrier(0);
        float l0 = blv, l1 = 0.f, r0 = brv, r1 = 0.f;
#pragma unroll
        for (int k = 0; k < 16; ++k) {
            l0 = fmaf(va[k], wl[k], l0);
            r0 = fmaf(va[k], wr[k], r0);
            l1 = fmaf(vb[k], wl[16 + k], l1);
            r1 = fmaf(vb[k], wr[16 + k], r1);
            l0 = fmaf(vc[k], wl[32 + k], l0);
            r0 = fmaf(vc[k], wr[32 + k], r0);
            l1 = fmaf(vd[k], wl[48 + k], l1);
            r1 = fmaf(vd[k], wr[48 + k], r1);
        }
        outL[(size_t)node * EMB + lane] = l0 + l1;
        outR[(size_t)node * EMB + lane] = r0 + r1;
    }
}

// finalize: bucket b's edges at epart[b*CAP .. b*CAP+cnt); slots for its 128
// nodes at ssrc[b*SCAP ..]. Writes offs (start) and eoffs (end) per node.
__global__ void finalize_kernel(const int* __restrict__ epart, const int* __restrict__ bcursor,
                                int* __restrict__ offs, int* __restrict__ eoffs,
                                int* __restrict__ ssrc, int N, int S /* pad start */) {
    __shared__ int deg4[4][BSZ];
    __shared__ int pos[BSZ];
    __shared__ int cur4[4][BSZ];
    int b = blockIdx.x;
    int t = threadIdx.x;
    int w = t >> 6;
    int n0 = b << BSH;
    int cnt = bcursor[b];
    int r0 = b * CAP, r1 = r0 + cnt;
    int sbase = b * SCAP;
    if (b == 0 && t < 128) ssrc[S + t] = 0;
    ((int*)deg4)[t] = 0;
    ((int*)deg4)[t + 256] = 0;
    __syncthreads();
    for (int e = r0 + t; e < r1; e += 256)
        atomicAdd(&deg4[w][epart[e] & (BSZ - 1)], 1);
    __syncthreads();
    int d0 = 0, d1 = 0, d2 = 0, sum = 0;
    if (t < BSZ) {
        d0 = deg4[0][t]; d1 = deg4[1][t]; d2 = deg4[2][t];
        sum = d0 + d1 + d2 + deg4[3][t];
        pos[t] = sum;
    }
    __syncthreads();
    for (int off = 1; off < BSZ; off <<= 1) {
        int v = (t < BSZ && t >= off) ? pos[t - off] : 0;
        __syncthreads();
        if (t < BSZ) pos[t] += v;
        __syncthreads();
    }
    if (t < BSZ) {
        int node = n0 + t;
        int base = sbase + (pos[t] - sum) + t;   // edges-before + self-slots-before
        if (node < N) {
            offs[node] = base;
            eoffs[node] = base + 1 + sum;        // end of this node's range
            ssrc[base] = node;                   // self-loop at slot 0
        }
        cur4[0][t] = base + 1;
        cur4[1][t] = base + 1 + d0;
        cur4[2][t] = base + 1 + d0 + d1;
        cur4[3][t] = base + 1 + d0 + d1 + d2;
    }
    __syncthreads();
    for (int e = r0 + t; e < r1; e += 256) {
        int v = epart[e];
        int s = atomicAdd(&cur4[w][v & (BSZ - 1)], 1);
        ssrc[s] = v >> BSH;
    }
}

// ---------------- DPP cross-lane add (VALU pipe; compiler handles hazards) --
template <int CTRL>
__device__ __forceinline__ float dpp_add(float v) {
    union { float f; int i; } u, r;
    u.f = v;
    r.i = __builtin_amdgcn_update_dpp(0, u.i, CTRL, 0xF, 0xF, true);
    return v + r.f;
}

// ---------------- GATv2 layer: 8 edges per wave iteration, pipelined --------
// R17 lesson: tail-slot index CLAMP to `wid` (L1-hot own row) is load-bearing.
// e0/e1 now come from separate offs/eoffs arrays (holes between buckets).
template <int L>
__global__ void gat_kernel(const float* __restrict__ xl, const float* __restrict__ xr,
                           const int* __restrict__ offs, const int* __restrict__ eoffs,
                           const int* __restrict__ ssrc,
                           const float* __restrict__ att, const float* __restrict__ bias,
                           const float* __restrict__ linW, const float* __restrict__ linb,
                           float* __restrict__ out, int N) {
    int wid = blockIdx.x * 4 + (threadIdx.x >> 6);
    int lane = threadIdx.x & 63;
    if (wid >= N) return;
    int grp = lane >> 4;          // edge slot within the 4-wide half-batch
    int li = lane & 15;           // float4 channel slot
    unsigned cb = (unsigned)li << 2;

    const float LOG2E = 1.4426950408889634f;
    float4 att4 = *(const float4*)(att + cb);
    att4.x *= LOG2E; att4.y *= LOG2E; att4.z *= LOG2E; att4.w *= LOG2E;
    float4 bias4 = *(const float4*)(bias + cb);
    unsigned rb = (unsigned)wid << 6;
    float4 xr4 = *(const float4*)(xr + rb + cb);

    int e0 = offs[wid], e1 = eoffs[wid];
    int e1a = e1 - grp;           // t+grp < e1    <=>  t < e1a
    int e1b = e1 - 4 - grp;       // t+4+grp < e1  <=>  t < e1b

    float s = 0.f;
    float4 acc = {0.f, 0.f, 0.f, 0.f};

    // prologue (allocated pad -> unconditional loads OK; clamp to hot own-row)
    unsigned sA = (unsigned)ssrc[e0 + grp];
    unsigned sB = (unsigned)ssrc[e0 + 4 + grp];
    sA = (e0 < e1a) ? sA : (unsigned)wid;
    sB = (e0 < e1b) ? sB : (unsigned)wid;

    for (int t = e0; t < e1; t += 8) {
        float4 a = *(const float4*)(xl + (sA << 6) + cb);
        float4 b = *(const float4*)(xl + (sB << 6) + cb);
        int tn = t + 8;
        unsigned nA = (unsigned)ssrc[tn + grp];
        unsigned nB = (unsigned)ssrc[tn + 4 + grp];
        nA = (tn < e1a) ? nA : (unsigned)wid;
        nB = (tn < e1b) ? nB : (unsigned)wid;
        bool vA = t < e1a;
        bool vB = t < e1b;

        float ux = a.x + xr4.x; ux = fmaxf(ux, 0.2f * ux);
        float uy = a.y + xr4.y; uy = fmaxf(uy, 0.2f * uy);
        float uz = a.z + xr4.z; uz = fmaxf(uz, 0.2f * uz);
        float uw = a.w + xr4.w; uw = fmaxf(uw, 0.2f * uw);
        float pa = att4.x * ux + att4.y * uy + att4.z * uz + att4.w * uw;
        pa = dpp_add<0xB1>(pa);
        pa = dpp_add<0x4E>(pa);
        if (L == 2) {
            pa = dpp_add<0x141>(pa);
            pa = dpp_add<0x140>(pa);
        }
        float pA = exp2f(pa);
        pA = vA ? pA : 0.f;
        s += pA;
        acc.x += pA * a.x; acc.y += pA * a.y; acc.z += pA * a.z; acc.w += pA * a.w;

        float vx = b.x + xr4.x; vx = fmaxf(vx, 0.2f * vx);
        float vy = b.y + xr4.y; vy = fmaxf(vy, 0.2f * vy);
        float vz = b.z + xr4.z; vz = fmaxf(vz, 0.2f * vz);
        float vw = b.w + xr4.w; vw = fmaxf(vw, 0.2f * vw);
        float pb = att4.x * vx + att4.y * vy + att4.z * vz + att4.w * vw;
        pb = dpp_add<0xB1>(pb);
        pb = dpp_add<0x4E>(pb);
        if (L == 2) {
            pb = dpp_add<0x141>(pb);
            pb = dpp_add<0x140>(pb);
        }
        float pB = exp2f(pb);
        pB = vB ? pB : 0.f;
        s += pB;
        acc.x += pB * b.x; acc.y += pB * b.y; acc.z += pB * b.z; acc.w += pB * b.w;

        sA = nA; sB = nB;
    }

    // combine the 4 edge groups (once per node)
    s += __shfl_xor(s, 16); s += __shfl_xor(s, 32);
    acc.x += __shfl_xor(acc.x, 16); acc.x += __shfl_xor(acc.x, 32);
    acc.y += __shfl_xor(acc.y, 16); acc.y += __shfl_xor(acc.y, 32);
    acc.z += __shfl_xor(acc.z, 16); acc.z += __shfl_xor(acc.z, 32);
    acc.w += __shfl_xor(acc.w, 16); acc.w += __shfl_xor(acc.w, 32);

    float inv = 1.f / (s + 1e-16f);
    if (L == 1) {
        float4 val;
        val.x = acc.x * inv + bias4.x;
        val.y = acc.y * inv + bias4.y;
        val.z = acc.z * inv + bias4.z;
        val.w = acc.w * inv + bias4.w;
        val.x = (val.x > 0.f) ? val.x : (__expf(val.x) - 1.f);
        val.y = (val.y > 0.f) ? val.y : (__expf(val.y) - 1.f);
        val.z = (val.z > 0.f) ? val.z : (__expf(val.z) - 1.f);
        val.w = (val.w > 0.f) ? val.w : (__expf(val.w) - 1.f);
        if (grp == 0) *(float4*)(out + rb + cb) = val;
    } else {
        float4 lw = *(const float4*)(linW + cb);
        float r = (acc.x * inv + bias4.x) * lw.x + (acc.y * inv + bias4.y) * lw.y +
                  (acc.z * inv + bias4.z) * lw.z + (acc.w * inv + bias4.w) * lw.w;
        r = dpp_add<0xB1>(r);
        r = dpp_add<0x4E>(r);
        r = dpp_add<0x141>(r);
        r = dpp_add<0x140>(r);
        if (lane == 0) out[wid] = r + linb[0];
    }
}

extern "C" void kernel_launch(void* const* d_in, const int* in_sizes, int n_in,
                              void* d_out, int out_size, void* d_ws, size_t ws_size,
                              hipStream_t stream) {
    const int* x = (const int*)d_in[0];
    const int* ei = (const int*)d_in[1];          // int32 marshalled
    const float* birth_tab = (const float*)d_in[2];
    const float* gender_tab = (const float*)d_in[3];
    const float* symp_tab = (const float*)d_in[4];
    const float* Wl1 = (const float*)d_in[5];
    const float* bl1 = (const float*)d_in[6];
    const float* Wr1 = (const float*)d_in[7];
    const float* br1 = (const float*)d_in[8];
    const float* att1 = (const float*)d_in[9];
    const float* bias1 = (const float*)d_in[10];
    const float* Wl2 = (const float*)d_in[11];
    const float* bl2 = (const float*)d_in[12];
    const float* Wr2 = (const float*)d_in[13];
    const float* br2 = (const float*)d_in[14];
    const float* att2 = (const float*)d_in[15];
    const float* bias2 = (const float*)d_in[16];
    const float* linW = (const float*)d_in[17];
    const float* linb = (const float*)d_in[18];
    float* outp = (float*)d_out;

    int N = in_sizes[0] / XCOLS;   // 100000
    int E = in_sizes[1] / 2;       // 1600000
    int NB = (N + BSZ - 1) >> BSH; // 782

    char* p = (char*)d_ws;
    auto alloc = [&](size_t bytes) {
        void* r = (void*)p;
        p += (bytes + 255) & ~(size_t)255;
        return r;
    };
    float* h0 = (float*)alloc((size_t)N * EMB * 4);
    float* bufA = (float*)alloc((size_t)N * EMB * 4);
    float* bufB = (float*)alloc((size_t)N * EMB * 4);
    int* bcursor = (int*)alloc(MAXNB * 4);
    int* offs = (int*)alloc((size_t)N * 4);
    int* eoffs = (int*)alloc((size_t)N * 4);
    int* ssrc = (int*)alloc(((size_t)NB * SCAP + 256) * 4);
    float* tL = (float*)alloc((size_t)TROWS * EMB * 4);
    float* tR = (float*)alloc((size_t)TROWS * EMB * 4);
    int* epart = (int*)h0;   // alias: epart (NB*CAP = 8MB) dead before gat1 writes h0

    int ngrp = (N + 3) / 4;
    int PB = (E + PCHUNK - 1) / PCHUNK;   // 391

    hipMemsetAsync(bcursor, 0, MAXNB * 4, stream);
    transform_kernel<<<TROWS, 64, 0, stream>>>(birth_tab, gender_tab, symp_tab,
                                               Wl1, Wr1, tL, tR);
    // partition + embedgemm run concurrently (block-role split)
    partition_embed_kernel<<<PB + ngrp, 256, 0, stream>>>(ei, bcursor, epart, E, NB, PB,
                                                          x, tL, tR, bl1, br1,
                                                          bufA, bufB, N);
    finalize_kernel<<<NB, 256, 0, stream>>>(epart, bcursor, offs, eoffs, ssrc, N,
                                            NB * SCAP);

    // node pipeline
    gat_kernel<1><<<ngrp, 256, 0, stream>>>(bufA, bufB, offs, eoffs, ssrc, att1, bias1,
                                            nullptr, nullptr, h0, N);
    gemm_dual_kernel<<<768, 256, 0, stream>>>(h0, Wl2, bl2, Wr2, br2, bufA, bufB, N);
    gat_kernel<2><<<ngrp, 256, 0, stream>>>(bufA, bufB, offs, eoffs, ssrc, att2, bias2,
                                            linW, linb, outp, N);
}

// Round 22
// 230.550 us; speedup vs baseline: 1.1690x; 1.0107x over previous
//
#include <hip/hip_runtime.h>
#include <hip/hip_bf16.h>

#define EMB 64
#define XCOLS 20
#define NSYMP 15
#define BSH 7
#define BSZ 128          // nodes per bucket (1<<BSH)
#define MAXNB 1024       // supports N <= 131072
#define PCHUNK 4096
#define TROWS 51         // 4 birth + 2 gender + 45 symp rows
#define CAP 2560         // fixed edge capacity per bucket (~11 sigma margin)
#define SCAP (CAP + BSZ) // slot capacity per bucket incl. self-loops

typedef float sf16 __attribute__((ext_vector_type(16)));

// ---------------- table transform (+ zero bcursor; saves a memset dispatch) --
__global__ void transform_kernel(const float* __restrict__ bt,
                                 const float* __restrict__ gt,
                                 const float* __restrict__ st,
                                 const float* __restrict__ Wl,
                                 const float* __restrict__ Wr,
                                 float* __restrict__ tL, float* __restrict__ tR,
                                 int* __restrict__ bcursor) {
    __shared__ float row[EMB];
    int r = blockIdx.x;          // 0..50
    int d = threadIdx.x;         // 64 threads
    int gi = r * 64 + d;
    if (gi < MAXNB) bcursor[gi] = 0;
    const float* src = (r < 4) ? (bt + r * EMB)
                     : (r < 6) ? (gt + (r - 4) * EMB)
                               : (st + (r - 6) * EMB);
    row[d] = src[d];
    __syncthreads();
    float aL = 0.f, aR = 0.f;
#pragma unroll
    for (int k = 0; k < EMB; ++k) {
        float h = row[k];
        aL = fmaf(h, Wl[k * EMB + d], aL);
        aR = fmaf(h, Wr[k * EMB + d], aR);
    }
    tL[r * EMB + d] = aL;
    tR[r * EMB + d] = aR;
}

// ---------------- partition + fused embedgemm (block-role split) ----------
// Partition role uses PER-WAVE sub-histograms/cursors (lh4[4][NB], 16 KB):
// phase1 histogram and phase3 scatter atomics contend only within a wave
// (R21 profile: 252K LDS bank conflicts from the shared-array version).
__global__ void partition_embed_kernel(const int* __restrict__ ei, int* __restrict__ bcursor,
                                       int* __restrict__ epart, int E, int NB, int PB,
                                       const int* __restrict__ x,
                                       const float* __restrict__ tL,
                                       const float* __restrict__ tR,
                                       const float* __restrict__ bl,
                                       const float* __restrict__ br,
                                       float* __restrict__ outL, float* __restrict__ outR,
                                       int N) {
    __shared__ int lh4[4][MAXNB];  // partition role (16 KB)
    __shared__ int xs[4 * XCOLS];  // embed role (320 B)
    if (blockIdx.x >= PB) {
        // ---- embedgemm role ----
        int bid = blockIdx.x - PB;
        int node = bid * 4 + (threadIdx.x >> 6);
        int d = threadIdx.x & 63;
        if (threadIdx.x < 4 * XCOLS) {
            int n2 = bid * 4 + threadIdx.x / XCOLS;
            xs[threadIdx.x] = (n2 < N) ? x[(size_t)bid * 4 * XCOLS + threadIdx.x] : 0;
        }
        __syncthreads();
        if (node >= N) return;
        const int* xr = &xs[(threadIdx.x >> 6) * XCOLS];
        int rbi = xr[1] + 2 * xr[2] + 3 * xr[3];   // birth row 0..3
        int rg = 4 + xr[4];                        // gender row 4..5
        float fL = 0.f, fR = 0.f;
#pragma unroll
        for (int j = 0; j < NSYMP; ++j) {
            int row = 6 + j * 3 + xr[5 + j];
            fL += tL[row * EMB + d];
            fR += tR[row * EMB + d];
        }
        float aL = (tL[rbi * EMB + d] + tL[rg * EMB + d] + fL * (1.f / 15.f)) * (1.f / 3.f) + bl[d];
        float aR = (tR[rbi * EMB + d] + tR[rg * EMB + d] + fR * (1.f / 15.f)) * (1.f / 3.f) + br[d];
        outL[node * EMB + d] = aL;
        outR[node * EMB + d] = aR;
        return;
    }
    // ---- partition role ----
    int w = threadIdx.x >> 6;
    for (int j = threadIdx.x; j < 4 * MAXNB; j += 256) ((int*)lh4)[j] = 0;
    __syncthreads();
    int base = blockIdx.x * PCHUNK;
    int end = min(E, base + PCHUNK);
    for (int i = base + threadIdx.x; i < end; i += 256)
        atomicAdd(&lh4[w][ei[E + i] >> BSH], 1);
    __syncthreads();
    for (int j = threadIdx.x; j < NB; j += 256) {
        int c0 = lh4[0][j], c1 = lh4[1][j], c2 = lh4[2][j], c3 = lh4[3][j];
        int tot = c0 + c1 + c2 + c3;
        int rb = tot ? (j * CAP + atomicAdd(&bcursor[j], tot)) : 0;
        lh4[0][j] = rb;
        lh4[1][j] = rb + c0;
        lh4[2][j] = rb + c0 + c1;
        lh4[3][j] = rb + c0 + c1 + c2;
    }
    __syncthreads();
    for (int i = base + threadIdx.x; i < end; i += 256) {
        int dst = ei[E + i];
        int src = ei[i];
        int slot = atomicAdd(&lh4[w][dst >> BSH], 1);
        epart[slot] = (src << BSH) | (dst & (BSZ - 1));
    }
}

// ---------------- dual GEMM v8: scalar-cache h broadcast + register weights --
__global__ __launch_bounds__(256, 3)
void gemm_dual_kernel(const float* __restrict__ h,
                      const float* __restrict__ Wl, const float* __restrict__ bl,
                      const float* __restrict__ Wr, const float* __restrict__ br,
                      float* __restrict__ outL, float* __restrict__ outR, int N) {
    int lane = threadIdx.x & 63;
    int wv = threadIdx.x >> 6;
    float wl[EMB], wr[EMB];
#pragma unroll
    for (int k = 0; k < EMB; ++k) {
        wl[k] = Wl[k * EMB + lane];
        wr[k] = Wr[k * EMB + lane];
    }
    float blv = bl[lane], brv = br[lane];
    int stride = gridDim.x * 4;
    for (int node = blockIdx.x * 4 + wv; node < N; node += stride) {
        int un = __builtin_amdgcn_readfirstlane(node);
        const float* hrow = h + (size_t)un * EMB;
        sf16 va, vb, vc, vd;
        asm volatile("s_load_dwordx16 %0, %1, 0x0"  : "=s"(va) : "s"(hrow));
        asm volatile("s_load_dwordx16 %0, %1, 0x40" : "=s"(vb) : "s"(hrow));
        asm volatile("s_load_dwordx16 %0, %1, 0x80" : "=s"(vc) : "s"(hrow));
        asm volatile("s_load_dwordx16 %0, %1, 0xc0" : "=s"(vd) : "s"(hrow));
        asm volatile("s_waitcnt lgkmcnt(0)" ::: "memory");
        __builtin_amdgcn_sched_barrier(0);
        float l0 = blv, l1 = 0.f, r0 = brv, r1 = 0.f;
#pragma unroll
        for (int k = 0; k < 16; ++k) {
            l0 = fmaf(va[k], wl[k], l0);
            r0 = fmaf(va[k], wr[k], r0);
            l1 = fmaf(vb[k], wl[16 + k], l1);
            r1 = fmaf(vb[k], wr[16 + k], r1);
            l0 = fmaf(vc[k], wl[32 + k], l0);
            r0 = fmaf(vc[k], wr[32 + k], r0);
            l1 = fmaf(vd[k], wl[48 + k], l1);
            r1 = fmaf(vd[k], wr[48 + k], r1);
        }
        outL[(size_t)node * EMB + lane] = l0 + l1;
        outR[(size_t)node * EMB + lane] = r0 + r1;
    }
}

// finalize: bucket b's edges at epart[b*CAP .. b*CAP+cnt); slots for its 128
// nodes at ssrc[b*SCAP ..]. Writes offs (start) and eoffs (end) per node.
__global__ void finalize_kernel(const int* __restrict__ epart, const int* __restrict__ bcursor,
                                int* __restrict__ offs, int* __restrict__ eoffs,
                                int* __restrict__ ssrc, int N, int S /* pad start */) {
    __shared__ int deg4[4][BSZ];
    __shared__ int pos[BSZ];
    __shared__ int cur4[4][BSZ];
    int b = blockIdx.x;
    int t = threadIdx.x;
    int w = t >> 6;
    int n0 = b << BSH;
    int cnt = bcursor[b];
    int r0 = b * CAP, r1 = r0 + cnt;
    int sbase = b * SCAP;
    if (b == 0 && t < 128) ssrc[S + t] = 0;
    ((int*)deg4)[t] = 0;
    ((int*)deg4)[t + 256] = 0;
    __syncthreads();
    for (int e = r0 + t; e < r1; e += 256)
        atomicAdd(&deg4[w][epart[e] & (BSZ - 1)], 1);
    __syncthreads();
    int d0 = 0, d1 = 0, d2 = 0, sum = 0;
    if (t < BSZ) {
        d0 = deg4[0][t]; d1 = deg4[1][t]; d2 = deg4[2][t];
        sum = d0 + d1 + d2 + deg4[3][t];
        pos[t] = sum;
    }
    __syncthreads();
    for (int off = 1; off < BSZ; off <<= 1) {
        int v = (t < BSZ && t >= off) ? pos[t - off] : 0;
        __syncthreads();
        if (t < BSZ) pos[t] += v;
        __syncthreads();
    }
    if (t < BSZ) {
        int node = n0 + t;
        int base = sbase + (pos[t] - sum) + t;   // edges-before + self-slots-before
        if (node < N) {
            offs[node] = base;
            eoffs[node] = base + 1 + sum;        // end of this node's range
            ssrc[base] = node;                   // self-loop at slot 0
        }
        cur4[0][t] = base + 1;
        cur4[1][t] = base + 1 + d0;
        cur4[2][t] = base + 1 + d0 + d1;
        cur4[3][t] = base + 1 + d0 + d1 + d2;
    }
    __syncthreads();
    for (int e = r0 + t; e < r1; e += 256) {
        int v = epart[e];
        int s = atomicAdd(&cur4[w][v & (BSZ - 1)], 1);
        ssrc[s] = v >> BSH;
    }
}

// ---------------- DPP cross-lane add (VALU pipe; compiler handles hazards) --
template <int CTRL>
__device__ __forceinline__ float dpp_add(float v) {
    union { float f; int i; } u, r;
    u.f = v;
    r.i = __builtin_amdgcn_update_dpp(0, u.i, CTRL, 0xF, 0xF, true);
    return v + r.f;
}

// ---------------- GATv2 layer: 8 edges per wave iteration, pipelined --------
// R17 lesson: tail-slot index CLAMP to `wid` (L1-hot own row) is load-bearing.
template <int L>
__global__ void gat_kernel(const float* __restrict__ xl, const float* __restrict__ xr,
                           const int* __restrict__ offs, const int* __restrict__ eoffs,
                           const int* __restrict__ ssrc,
                           const float* __restrict__ att, const float* __restrict__ bias,
                           const float* __restrict__ linW, const float* __restrict__ linb,
                           float* __restrict__ out, int N) {
    int wid = blockIdx.x * 4 + (threadIdx.x >> 6);
    int lane = threadIdx.x & 63;
    if (wid >= N) return;
    int grp = lane >> 4;          // edge slot within the 4-wide half-batch
    int li = lane & 15;           // float4 channel slot
    unsigned cb = (unsigned)li << 2;

    const float LOG2E = 1.4426950408889634f;
    float4 att4 = *(const float4*)(att + cb);
    att4.x *= LOG2E; att4.y *= LOG2E; att4.z *= LOG2E; att4.w *= LOG2E;
    float4 bias4 = *(const float4*)(bias + cb);
    unsigned rb = (unsigned)wid << 6;
    float4 xr4 = *(const float4*)(xr + rb + cb);

    int e0 = offs[wid], e1 = eoffs[wid];
    int e1a = e1 - grp;           // t+grp < e1    <=>  t < e1a
    int e1b = e1 - 4 - grp;       // t+4+grp < e1  <=>  t < e1b

    float s = 0.f;
    float4 acc = {0.f, 0.f, 0.f, 0.f};

    // prologue (allocated pad -> unconditional loads OK; clamp to hot own-row)
    unsigned sA = (unsigned)ssrc[e0 + grp];
    unsigned sB = (unsigned)ssrc[e0 + 4 + grp];
    sA = (e0 < e1a) ? sA : (unsigned)wid;
    sB = (e0 < e1b) ? sB : (unsigned)wid;

    for (int t = e0; t < e1; t += 8) {
        float4 a = *(const float4*)(xl + (sA << 6) + cb);
        float4 b = *(const float4*)(xl + (sB << 6) + cb);
        int tn = t + 8;
        unsigned nA = (unsigned)ssrc[tn + grp];
        unsigned nB = (unsigned)ssrc[tn + 4 + grp];
        nA = (tn < e1a) ? nA : (unsigned)wid;
        nB = (tn < e1b) ? nB : (unsigned)wid;
        bool vA = t < e1a;
        bool vB = t < e1b;

        float ux = a.x + xr4.x; ux = fmaxf(ux, 0.2f * ux);
        float uy = a.y + xr4.y; uy = fmaxf(uy, 0.2f * uy);
        float uz = a.z + xr4.z; uz = fmaxf(uz, 0.2f * uz);
        float uw = a.w + xr4.w; uw = fmaxf(uw, 0.2f * uw);
        float pa = att4.x * ux + att4.y * uy + att4.z * uz + att4.w * uw;
        pa = dpp_add<0xB1>(pa);
        pa = dpp_add<0x4E>(pa);
        if (L == 2) {
            pa = dpp_add<0x141>(pa);
            pa = dpp_add<0x140>(pa);
        }
        float pA = exp2f(pa);
        pA = vA ? pA : 0.f;
        s += pA;
        acc.x += pA * a.x; acc.y += pA * a.y; acc.z += pA * a.z; acc.w += pA * a.w;

        float vx = b.x + xr4.x; vx = fmaxf(vx, 0.2f * vx);
        float vy = b.y + xr4.y; vy = fmaxf(vy, 0.2f * vy);
        float vz = b.z + xr4.z; vz = fmaxf(vz, 0.2f * vz);
        float vw = b.w + xr4.w; vw = fmaxf(vw, 0.2f * vw);
        float pb = att4.x * vx + att4.y * vy + att4.z * vz + att4.w * vw;
        pb = dpp_add<0xB1>(pb);
        pb = dpp_add<0x4E>(pb);
        if (L == 2) {
            pb = dpp_add<0x141>(pb);
            pb = dpp_add<0x140>(pb);
        }
        float pB = exp2f(pb);
        pB = vB ? pB : 0.f;
        s += pB;
        acc.x += pB * b.x; acc.y += pB * b.y; acc.z += pB * b.z; acc.w += pB * b.w;

        sA = nA; sB = nB;
    }

    // combine the 4 edge groups (once per node)
    s += __shfl_xor(s, 16); s += __shfl_xor(s, 32);
    acc.x += __shfl_xor(acc.x, 16); acc.x += __shfl_xor(acc.x, 32);
    acc.y += __shfl_xor(acc.y, 16); acc.y += __shfl_xor(acc.y, 32);
    acc.z += __shfl_xor(acc.z, 16); acc.z += __shfl_xor(acc.z, 32);
    acc.w += __shfl_xor(acc.w, 16); acc.w += __shfl_xor(acc.w, 32);

    float inv = 1.f / (s + 1e-16f);
    if (L == 1) {
        float4 val;
        val.x = acc.x * inv + bias4.x;
        val.y = acc.y * inv + bias4.y;
        val.z = acc.z * inv + bias4.z;
        val.w = acc.w * inv + bias4.w;
        val.x = (val.x > 0.f) ? val.x : (__expf(val.x) - 1.f);
        val.y = (val.y > 0.f) ? val.y : (__expf(val.y) - 1.f);
        val.z = (val.z > 0.f) ? val.z : (__expf(val.z) - 1.f);
        val.w = (val.w > 0.f) ? val.w : (__expf(val.w) - 1.f);
        if (grp == 0) *(float4*)(out + rb + cb) = val;
    } else {
        float4 lw = *(const float4*)(linW + cb);
        float r = (acc.x * inv + bias4.x) * lw.x + (acc.y * inv + bias4.y) * lw.y +
                  (acc.z * inv + bias4.z) * lw.z + (acc.w * inv + bias4.w) * lw.w;
        r = dpp_add<0xB1>(r);
        r = dpp_add<0x4E>(r);
        r = dpp_add<0x141>(r);
        r = dpp_add<0x140>(r);
        if (lane == 0) out[wid] = r + linb[0];
    }
}

extern "C" void kernel_launch(void* const* d_in, const int* in_sizes, int n_in,
                              void* d_out, int out_size, void* d_ws, size_t ws_size,
                              hipStream_t stream) {
    const int* x = (const int*)d_in[0];
    const int* ei = (const int*)d_in[1];          // int32 marshalled
    const float* birth_tab = (const float*)d_in[2];
    const float* gender_tab = (const float*)d_in[3];
    const float* symp_tab = (const float*)d_in[4];
    const float* Wl1 = (const float*)d_in[5];
    const float* bl1 = (const float*)d_in[6];
    const float* Wr1 = (const float*)d_in[7];
    const float* br1 = (const float*)d_in[8];
    const float* att1 = (const float*)d_in[9];
    const float* bias1 = (const float*)d_in[10];
    const float* Wl2 = (const float*)d_in[11];
    const float* bl2 = (const float*)d_in[12];
    const float* Wr2 = (const float*)d_in[13];
    const float* br2 = (const float*)d_in[14];
    const float* att2 = (const float*)d_in[15];
    const float* bias2 = (const float*)d_in[16];
    const float* linW = (const float*)d_in[17];
    const float* linb = (const float*)d_in[18];
    float* outp = (float*)d_out;

    int N = in_sizes[0] / XCOLS;   // 100000
    int E = in_sizes[1] / 2;       // 1600000
    int NB = (N + BSZ - 1) >> BSH; // 782

    char* p = (char*)d_ws;
    auto alloc = [&](size_t bytes) {
        void* r = (void*)p;
        p += (bytes + 255) & ~(size_t)255;
        return r;
    };
    float* h0 = (float*)alloc((size_t)N * EMB * 4);
    float* bufA = (float*)alloc((size_t)N * EMB * 4);
    float* bufB = (float*)alloc((size_t)N * EMB * 4);
    int* bcursor = (int*)alloc(MAXNB * 4);
    int* offs = (int*)alloc((size_t)N * 4);
    int* eoffs = (int*)alloc((size_t)N * 4);
    int* ssrc = (int*)alloc(((size_t)NB * SCAP + 256) * 4);
    float* tL = (float*)alloc((size_t)TROWS * EMB * 4);
    float* tR = (float*)alloc((size_t)TROWS * EMB * 4);
    int* epart = (int*)h0;   // alias: epart (NB*CAP = 8MB) dead before gat1 writes h0

    int ngrp = (N + 3) / 4;
    int PB = (E + PCHUNK - 1) / PCHUNK;   // 391

    transform_kernel<<<TROWS, 64, 0, stream>>>(birth_tab, gender_tab, symp_tab,
                                               Wl1, Wr1, tL, tR, bcursor);
    // partition + embedgemm run concurrently (block-role split)
    partition_embed_kernel<<<PB + ngrp, 256, 0, stream>>>(ei, bcursor, epart, E, NB, PB,
                                                          x, tL, tR, bl1, br1,
                                                          bufA, bufB, N);
    finalize_kernel<<<NB, 256, 0, stream>>>(epart, bcursor, offs, eoffs, ssrc, N,
                                            NB * SCAP);

    // node pipeline
    gat_kernel<1><<<ngrp, 256, 0, stream>>>(bufA, bufB, offs, eoffs, ssrc, att1, bias1,
                                            nullptr, nullptr, h0, N);
    gemm_dual_kernel<<<768, 256, 0, stream>>>(h0, Wl2, bl2, Wr2, br2, bufA, bufB, N);
    gat_kernel<2><<<ngrp, 256, 0, stream>>>(bufA, bufB, offs, eoffs, ssrc, att2, bias2,
                                            linW, linb, outp, N);
}

// Round 23
// 229.578 us; speedup vs baseline: 1.1740x; 1.0042x over previous
//
#include <hip/hip_runtime.h>
#include <hip/hip_bf16.h>

#define EMB 64
#define XCOLS 20
#define NSYMP 15
#define BSH 7
#define BSZ 128          // nodes per bucket (1<<BSH)
#define MAXNB 1024       // supports N <= 131072
#define PCHUNK 4096
#define TROWS 51         // 4 birth + 2 gender + 45 symp rows
#define CAP 2560         // fixed edge capacity per bucket (~11 sigma margin)
#define SCAP (CAP + BSZ) // slot capacity per bucket incl. self-loops

typedef float sf16 __attribute__((ext_vector_type(16)));

// ---------------- table transform (+ zero bcursor; saves a memset dispatch) --
__global__ void transform_kernel(const float* __restrict__ bt,
                                 const float* __restrict__ gt,
                                 const float* __restrict__ st,
                                 const float* __restrict__ Wl,
                                 const float* __restrict__ Wr,
                                 float* __restrict__ tL, float* __restrict__ tR,
                                 int* __restrict__ bcursor) {
    __shared__ float row[EMB];
    int r = blockIdx.x;          // 0..50
    int d = threadIdx.x;         // 64 threads
    int gi = r * 64 + d;
    if (gi < MAXNB) bcursor[gi] = 0;
    const float* src = (r < 4) ? (bt + r * EMB)
                     : (r < 6) ? (gt + (r - 4) * EMB)
                               : (st + (r - 6) * EMB);
    row[d] = src[d];
    __syncthreads();
    float aL = 0.f, aR = 0.f;
#pragma unroll
    for (int k = 0; k < EMB; ++k) {
        float h = row[k];
        aL = fmaf(h, Wl[k * EMB + d], aL);
        aR = fmaf(h, Wr[k * EMB + d], aR);
    }
    tL[r * EMB + d] = aL;
    tR[r * EMB + d] = aR;
}

// ---------------- partition + fused embedgemm (block-role split, 512 thr) ---
// R22 post-mortem: partition was parallelism-starved (391 blocks x 4 waves =
// 1.5 waves/SIMD once embed drains). 512-thread blocks double the in-flight
// waves (3128 = 3/SIMD) with phase-2 atomic count and write-run length
// UNCHANGED (per-block properties). lh8[8][NB] = per-wave sub-hist (32 KB).
__global__ void partition_embed_kernel(const int* __restrict__ ei, int* __restrict__ bcursor,
                                       int* __restrict__ epart, int E, int NB, int PB,
                                       const int* __restrict__ x,
                                       const float* __restrict__ tL,
                                       const float* __restrict__ tR,
                                       const float* __restrict__ bl,
                                       const float* __restrict__ br,
                                       float* __restrict__ outL, float* __restrict__ outR,
                                       int N) {
    __shared__ int lh8[8][MAXNB];  // partition role (32 KB)
    __shared__ int xs[8 * XCOLS];  // embed role (640 B)
    if (blockIdx.x >= PB) {
        // ---- embedgemm role: 8 nodes per 512-thread block ----
        int bid = blockIdx.x - PB;
        int node = bid * 8 + (threadIdx.x >> 6);
        int d = threadIdx.x & 63;
        if (threadIdx.x < 8 * XCOLS) {
            int n2 = bid * 8 + threadIdx.x / XCOLS;
            xs[threadIdx.x] = (n2 < N) ? x[(size_t)bid * 8 * XCOLS + threadIdx.x] : 0;
        }
        __syncthreads();
        if (node >= N) return;
        const int* xr = &xs[(threadIdx.x >> 6) * XCOLS];
        int rbi = xr[1] + 2 * xr[2] + 3 * xr[3];   // birth row 0..3
        int rg = 4 + xr[4];                        // gender row 4..5
        float fL = 0.f, fR = 0.f;
#pragma unroll
        for (int j = 0; j < NSYMP; ++j) {
            int row = 6 + j * 3 + xr[5 + j];
            fL += tL[row * EMB + d];
            fR += tR[row * EMB + d];
        }
        float aL = (tL[rbi * EMB + d] + tL[rg * EMB + d] + fL * (1.f / 15.f)) * (1.f / 3.f) + bl[d];
        float aR = (tR[rbi * EMB + d] + tR[rg * EMB + d] + fR * (1.f / 15.f)) * (1.f / 3.f) + br[d];
        outL[node * EMB + d] = aL;
        outR[node * EMB + d] = aR;
        return;
    }
    // ---- partition role ----
    int w = threadIdx.x >> 6;      // wave 0..7
    for (int j = threadIdx.x; j < 8 * MAXNB; j += 512) ((int*)lh8)[j] = 0;
    __syncthreads();
    int base = blockIdx.x * PCHUNK;
    int end = min(E, base + PCHUNK);
    for (int i = base + threadIdx.x; i < end; i += 512)
        atomicAdd(&lh8[w][ei[E + i] >> BSH], 1);
    __syncthreads();
    for (int j = threadIdx.x; j < NB; j += 512) {
        int c[8];
        int tot = 0;
#pragma unroll
        for (int k = 0; k < 8; ++k) { c[k] = lh8[k][j]; tot += c[k]; }
        int rb = tot ? (j * CAP + atomicAdd(&bcursor[j], tot)) : 0;
#pragma unroll
        for (int k = 0; k < 8; ++k) { lh8[k][j] = rb; rb += c[k]; }
    }
    __syncthreads();
    for (int i = base + threadIdx.x; i < end; i += 512) {
        int dst = ei[E + i];
        int src = ei[i];
        int slot = atomicAdd(&lh8[w][dst >> BSH], 1);
        epart[slot] = (src << BSH) | (dst & (BSZ - 1));
    }
}

// ---------------- dual GEMM v8: scalar-cache h broadcast + register weights --
__global__ __launch_bounds__(256, 3)
void gemm_dual_kernel(const float* __restrict__ h,
                      const float* __restrict__ Wl, const float* __restrict__ bl,
                      const float* __restrict__ Wr, const float* __restrict__ br,
                      float* __restrict__ outL, float* __restrict__ outR, int N) {
    int lane = threadIdx.x & 63;
    int wv = threadIdx.x >> 6;
    float wl[EMB], wr[EMB];
#pragma unroll
    for (int k = 0; k < EMB; ++k) {
        wl[k] = Wl[k * EMB + lane];
        wr[k] = Wr[k * EMB + lane];
    }
    float blv = bl[lane], brv = br[lane];
    int stride = gridDim.x * 4;
    for (int node = blockIdx.x * 4 + wv; node < N; node += stride) {
        int un = __builtin_amdgcn_readfirstlane(node);
        const float* hrow = h + (size_t)un * EMB;
        sf16 va, vb, vc, vd;
        asm volatile("s_load_dwordx16 %0, %1, 0x0"  : "=s"(va) : "s"(hrow));
        asm volatile("s_load_dwordx16 %0, %1, 0x40" : "=s"(vb) : "s"(hrow));
        asm volatile("s_load_dwordx16 %0, %1, 0x80" : "=s"(vc) : "s"(hrow));
        asm volatile("s_load_dwordx16 %0, %1, 0xc0" : "=s"(vd) : "s"(hrow));
        asm volatile("s_waitcnt lgkmcnt(0)" ::: "memory");
        __builtin_amdgcn_sched_barrier(0);
        float l0 = blv, l1 = 0.f, r0 = brv, r1 = 0.f;
#pragma unroll
        for (int k = 0; k < 16; ++k) {
            l0 = fmaf(va[k], wl[k], l0);
            r0 = fmaf(va[k], wr[k], r0);
            l1 = fmaf(vb[k], wl[16 + k], l1);
            r1 = fmaf(vb[k], wr[16 + k], r1);
            l0 = fmaf(vc[k], wl[32 + k], l0);
            r0 = fmaf(vc[k], wr[32 + k], r0);
            l1 = fmaf(vd[k], wl[48 + k], l1);
            r1 = fmaf(vd[k], wr[48 + k], r1);
        }
        outL[(size_t)node * EMB + lane] = l0 + l1;
        outR[(size_t)node * EMB + lane] = r0 + r1;
    }
}

// finalize: bucket b's edges at epart[b*CAP .. b*CAP+cnt); slots for its 128
// nodes at ssrc[b*SCAP ..]. Writes offs (start) and eoffs (end) per node.
__global__ void finalize_kernel(const int* __restrict__ epart, const int* __restrict__ bcursor,
                                int* __restrict__ offs, int* __restrict__ eoffs,
                                int* __restrict__ ssrc, int N, int S /* pad start */) {
    __shared__ int deg4[4][BSZ];
    __shared__ int pos[BSZ];
    __shared__ int cur4[4][BSZ];
    int b = blockIdx.x;
    int t = threadIdx.x;
    int w = t >> 6;
    int n0 = b << BSH;
    int cnt = bcursor[b];
    int r0 = b * CAP, r1 = r0 + cnt;
    int sbase = b * SCAP;
    if (b == 0 && t < 128) ssrc[S + t] = 0;
    ((int*)deg4)[t] = 0;
    ((int*)deg4)[t + 256] = 0;
    __syncthreads();
    for (int e = r0 + t; e < r1; e += 256)
        atomicAdd(&deg4[w][epart[e] & (BSZ - 1)], 1);
    __syncthreads();
    int d0 = 0, d1 = 0, d2 = 0, sum = 0;
    if (t < BSZ) {
        d0 = deg4[0][t]; d1 = deg4[1][t]; d2 = deg4[2][t];
        sum = d0 + d1 + d2 + deg4[3][t];
        pos[t] = sum;
    }
    __syncthreads();
    for (int off = 1; off < BSZ; off <<= 1) {
        int v = (t < BSZ && t >= off) ? pos[t - off] : 0;
        __syncthreads();
        if (t < BSZ) pos[t] += v;
        __syncthreads();
    }
    if (t < BSZ) {
        int node = n0 + t;
        int base = sbase + (pos[t] - sum) + t;   // edges-before + self-slots-before
        if (node < N) {
            offs[node] = base;
            eoffs[node] = base + 1 + sum;        // end of this node's range
            ssrc[base] = node;                   // self-loop at slot 0
        }
        cur4[0][t] = base + 1;
        cur4[1][t] = base + 1 + d0;
        cur4[2][t] = base + 1 + d0 + d1;
        cur4[3][t] = base + 1 + d0 + d1 + d2;
    }
    __syncthreads();
    for (int e = r0 + t; e < r1; e += 256) {
        int v = epart[e];
        int s = atomicAdd(&cur4[w][v & (BSZ - 1)], 1);
        ssrc[s] = v >> BSH;
    }
}

// ---------------- DPP cross-lane add (VALU pipe; compiler handles hazards) --
template <int CTRL>
__device__ __forceinline__ float dpp_add(float v) {
    union { float f; int i; } u, r;
    u.f = v;
    r.i = __builtin_amdgcn_update_dpp(0, u.i, CTRL, 0xF, 0xF, true);
    return v + r.f;
}

// ---------------- GATv2 layer: 8 edges per wave iteration, pipelined --------
// R17 lesson: tail-slot index CLAMP to `wid` (L1-hot own row) is load-bearing.
template <int L>
__global__ void gat_kernel(const float* __restrict__ xl, const float* __restrict__ xr,
                           const int* __restrict__ offs, const int* __restrict__ eoffs,
                           const int* __restrict__ ssrc,
                           const float* __restrict__ att, const float* __restrict__ bias,
                           const float* __restrict__ linW, const float* __restrict__ linb,
                           float* __restrict__ out, int N) {
    int wid = blockIdx.x * 4 + (threadIdx.x >> 6);
    int lane = threadIdx.x & 63;
    if (wid >= N) return;
    int grp = lane >> 4;          // edge slot within the 4-wide half-batch
    int li = lane & 15;           // float4 channel slot
    unsigned cb = (unsigned)li << 2;

    const float LOG2E = 1.4426950408889634f;
    float4 att4 = *(const float4*)(att + cb);
    att4.x *= LOG2E; att4.y *= LOG2E; att4.z *= LOG2E; att4.w *= LOG2E;
    float4 bias4 = *(const float4*)(bias + cb);
    unsigned rb = (unsigned)wid << 6;
    float4 xr4 = *(const float4*)(xr + rb + cb);

    int e0 = offs[wid], e1 = eoffs[wid];
    int e1a = e1 - grp;           // t+grp < e1    <=>  t < e1a
    int e1b = e1 - 4 - grp;       // t+4+grp < e1  <=>  t < e1b

    float s = 0.f;
    float4 acc = {0.f, 0.f, 0.f, 0.f};

    // prologue (allocated pad -> unconditional loads OK; clamp to hot own-row)
    unsigned sA = (unsigned)ssrc[e0 + grp];
    unsigned sB = (unsigned)ssrc[e0 + 4 + grp];
    sA = (e0 < e1a) ? sA : (unsigned)wid;
    sB = (e0 < e1b) ? sB : (unsigned)wid;

    for (int t = e0; t < e1; t += 8) {
        float4 a = *(const float4*)(xl + (sA << 6) + cb);
        float4 b = *(const float4*)(xl + (sB << 6) + cb);
        int tn = t + 8;
        unsigned nA = (unsigned)ssrc[tn + grp];
        unsigned nB = (unsigned)ssrc[tn + 4 + grp];
        nA = (tn < e1a) ? nA : (unsigned)wid;
        nB = (tn < e1b) ? nB : (unsigned)wid;
        bool vA = t < e1a;
        bool vB = t < e1b;

        float ux = a.x + xr4.x; ux = fmaxf(ux, 0.2f * ux);
        float uy = a.y + xr4.y; uy = fmaxf(uy, 0.2f * uy);
        float uz = a.z + xr4.z; uz = fmaxf(uz, 0.2f * uz);
        float uw = a.w + xr4.w; uw = fmaxf(uw, 0.2f * uw);
        float pa = att4.x * ux + att4.y * uy + att4.z * uz + att4.w * uw;
        pa = dpp_add<0xB1>(pa);
        pa = dpp_add<0x4E>(pa);
        if (L == 2) {
            pa = dpp_add<0x141>(pa);
            pa = dpp_add<0x140>(pa);
        }
        float pA = exp2f(pa);
        pA = vA ? pA : 0.f;
        s += pA;
        acc.x += pA * a.x; acc.y += pA * a.y; acc.z += pA * a.z; acc.w += pA * a.w;

        float vx = b.x + xr4.x; vx = fmaxf(vx, 0.2f * vx);
        float vy = b.y + xr4.y; vy = fmaxf(vy, 0.2f * vy);
        float vz = b.z + xr4.z; vz = fmaxf(vz, 0.2f * vz);
        float vw = b.w + xr4.w; vw = fmaxf(vw, 0.2f * vw);
        float pb = att4.x * vx + att4.y * vy + att4.z * vz + att4.w * vw;
        pb = dpp_add<0xB1>(pb);
        pb = dpp_add<0x4E>(pb);
        if (L == 2) {
            pb = dpp_add<0x141>(pb);
            pb = dpp_add<0x140>(pb);
        }
        float pB = exp2f(pb);
        pB = vB ? pB : 0.f;
        s += pB;
        acc.x += pB * b.x; acc.y += pB * b.y; acc.z += pB * b.z; acc.w += pB * b.w;

        sA = nA; sB = nB;
    }

    // combine the 4 edge groups (once per node)
    s += __shfl_xor(s, 16); s += __shfl_xor(s, 32);
    acc.x += __shfl_xor(acc.x, 16); acc.x += __shfl_xor(acc.x, 32);
    acc.y += __shfl_xor(acc.y, 16); acc.y += __shfl_xor(acc.y, 32);
    acc.z += __shfl_xor(acc.z, 16); acc.z += __shfl_xor(acc.z, 32);
    acc.w += __shfl_xor(acc.w, 16); acc.w += __shfl_xor(acc.w, 32);

    float inv = 1.f / (s + 1e-16f);
    if (L == 1) {
        float4 val;
        val.x = acc.x * inv + bias4.x;
        val.y = acc.y * inv + bias4.y;
        val.z = acc.z * inv + bias4.z;
        val.w = acc.w * inv + bias4.w;
        val.x = (val.x > 0.f) ? val.x : (__expf(val.x) - 1.f);
        val.y = (val.y > 0.f) ? val.y : (__expf(val.y) - 1.f);
        val.z = (val.z > 0.f) ? val.z : (__expf(val.z) - 1.f);
        val.w = (val.w > 0.f) ? val.w : (__expf(val.w) - 1.f);
        if (grp == 0) *(float4*)(out + rb + cb) = val;
    } else {
        float4 lw = *(const float4*)(linW + cb);
        float r = (acc.x * inv + bias4.x) * lw.x + (acc.y * inv + bias4.y) * lw.y +
                  (acc.z * inv + bias4.z) * lw.z + (acc.w * inv + bias4.w) * lw.w;
        r = dpp_add<0xB1>(r);
        r = dpp_add<0x4E>(r);
        r = dpp_add<0x141>(r);
        r = dpp_add<0x140>(r);
        if (lane == 0) out[wid] = r + linb[0];
    }
}

extern "C" void kernel_launch(void* const* d_in, const int* in_sizes, int n_in,
                              void* d_out, int out_size, void* d_ws, size_t ws_size,
                              hipStream_t stream) {
    const int* x = (const int*)d_in[0];
    const int* ei = (const int*)d_in[1];          // int32 marshalled
    const float* birth_tab = (const float*)d_in[2];
    const float* gender_tab = (const float*)d_in[3];
    const float* symp_tab = (const float*)d_in[4];
    const float* Wl1 = (const float*)d_in[5];
    const float* bl1 = (const float*)d_in[6];
    const float* Wr1 = (const float*)d_in[7];
    const float* br1 = (const float*)d_in[8];
    const float* att1 = (const float*)d_in[9];
    const float* bias1 = (const float*)d_in[10];
    const float* Wl2 = (const float*)d_in[11];
    const float* bl2 = (const float*)d_in[12];
    const float* Wr2 = (const float*)d_in[13];
    const float* br2 = (const float*)d_in[14];
    const float* att2 = (const float*)d_in[15];
    const float* bias2 = (const float*)d_in[16];
    const float* linW = (const float*)d_in[17];
    const float* linb = (const float*)d_in[18];
    float* outp = (float*)d_out;

    int N = in_sizes[0] / XCOLS;   // 100000
    int E = in_sizes[1] / 2;       // 1600000
    int NB = (N + BSZ - 1) >> BSH; // 782

    char* p = (char*)d_ws;
    auto alloc = [&](size_t bytes) {
        void* r = (void*)p;
        p += (bytes + 255) & ~(size_t)255;
        return r;
    };
    float* h0 = (float*)alloc((size_t)N * EMB * 4);
    float* bufA = (float*)alloc((size_t)N * EMB * 4);
    float* bufB = (float*)alloc((size_t)N * EMB * 4);
    int* bcursor = (int*)alloc(MAXNB * 4);
    int* offs = (int*)alloc((size_t)N * 4);
    int* eoffs = (int*)alloc((size_t)N * 4);
    int* ssrc = (int*)alloc(((size_t)NB * SCAP + 256) * 4);
    float* tL = (float*)alloc((size_t)TROWS * EMB * 4);
    float* tR = (float*)alloc((size_t)TROWS * EMB * 4);
    int* epart = (int*)h0;   // alias: epart (NB*CAP = 8MB) dead before gat1 writes h0

    int ngrp = (N + 3) / 4;
    int ngrp8 = (N + 7) / 8;
    int PB = (E + PCHUNK - 1) / PCHUNK;   // 391

    transform_kernel<<<TROWS, 64, 0, stream>>>(birth_tab, gender_tab, symp_tab,
                                               Wl1, Wr1, tL, tR, bcursor);
    // partition + embedgemm run concurrently (block-role split, 512 threads)
    partition_embed_kernel<<<PB + ngrp8, 512, 0, stream>>>(ei, bcursor, epart, E, NB, PB,
                                                           x, tL, tR, bl1, br1,
                                                           bufA, bufB, N);
    finalize_kernel<<<NB, 256, 0, stream>>>(epart, bcursor, offs, eoffs, ssrc, N,
                                            NB * SCAP);

    // node pipeline
    gat_kernel<1><<<ngrp, 256, 0, stream>>>(bufA, bufB, offs, eoffs, ssrc, att1, bias1,
                                            nullptr, nullptr, h0, N);
    gemm_dual_kernel<<<768, 256, 0, stream>>>(h0, Wl2, bl2, Wr2, br2, bufA, bufB, N);
    gat_kernel<2><<<ngrp, 256, 0, stream>>>(bufA, bufB, offs, eoffs, ssrc, att2, bias2,
                                            linW, linb, outp, N);
}